// Round 1
// 892.760 us; speedup vs baseline: 1.0859x; 1.0859x over previous
//
#include <hip/hip_runtime.h>

#define N_MI 100000
#define N_DI 50000
#define MI_P 100352   // multiple of 256
#define DI_P 50176    // multiple of 256

#define SCAN_CHUNK 2048
#define NB_DI ((N_DI + SCAN_CHUNK - 1) / SCAN_CHUNK)   // 25
#define NB_MI ((N_MI + SCAN_CHUNK - 1) / SCAN_CHUNK)   // 49

typedef _Float16 half8  __attribute__((ext_vector_type(8)));
typedef _Float16 half4  __attribute__((ext_vector_type(4)));
typedef float    floatx4 __attribute__((ext_vector_type(4)));

// ---------------------------------------------------------------------------
// CSR build
// ---------------------------------------------------------------------------
__global__ void count_kernel(const int* __restrict__ src, const int* __restrict__ dst,
                             int* deg_mi, int* deg_di, int E) {
    int i = blockIdx.x * blockDim.x + threadIdx.x;
    if (i < E) {
        atomicAdd(&deg_mi[src[i]], 1);
        atomicAdd(&deg_di[dst[i]], 1);
    }
}

// Hierarchical scan, stage 1: each block scans a 2048-element chunk.
// blockIdx.y: 0 -> di, 1 -> mi. Writes block-local exclusive prefix into row[]
// and the block total into bsum[64*y + blockIdx.x].
__global__ __launch_bounds__(256) void scan_part_kernel(const int* __restrict__ deg_di,
                                                        const int* __restrict__ deg_mi,
                                                        int* __restrict__ row_di,
                                                        int* __restrict__ row_mi,
                                                        int* __restrict__ bsum) {
    const int* deg; int* row; int n; int* bs;
    if (blockIdx.y == 0) { deg = deg_di; row = row_di; n = N_DI; bs = bsum; }
    else                 { deg = deg_mi; row = row_mi; n = N_MI; bs = bsum + 64; }
    int nb = (n + SCAN_CHUNK - 1) / SCAN_CHUNK;
    if ((int)blockIdx.x >= nb) return;
    int t = threadIdx.x;
    int base = blockIdx.x * SCAN_CHUNK + t * 8;
    int v[8]; int s = 0;
    #pragma unroll
    for (int e = 0; e < 8; ++e) {
        int i = base + e;
        v[e] = (i < n) ? deg[i] : 0;
        s += v[e];
    }
    int lane = t & 63, w = t >> 6;
    int x = s;
    #pragma unroll
    for (int off = 1; off < 64; off <<= 1) {
        int y = __shfl_up(x, off, 64);
        if (lane >= off) x += y;
    }
    __shared__ int wsum[4];
    if (lane == 63) wsum[w] = x;
    __syncthreads();
    int woff = 0;
    #pragma unroll
    for (int i = 0; i < 3; ++i) if (i < w) woff += wsum[i];
    int run = woff + x - s;      // exclusive prefix of this thread's first element
    #pragma unroll
    for (int e = 0; e < 8; ++e) {
        int i = base + e;
        if (i < n) row[i] = run;
        run += v[e];
    }
    if (t == 255) bs[blockIdx.x] = woff + x;   // block total
}

// Stage 2: scan the per-block sums. Wave 0 -> di (25 sums), wave 1 -> mi (49).
// Converts bsum[] to exclusive block offsets and writes row[n] totals.
__global__ void scan_sums_kernel(int* __restrict__ bsum, int* __restrict__ row_di,
                                 int* __restrict__ row_mi) {
    int w = threadIdx.x >> 6, lane = threadIdx.x & 63;
    int nb = (w == 0) ? NB_DI : NB_MI;
    int* bs = bsum + w * 64;
    int v = (lane < nb) ? bs[lane] : 0;
    int x = v;
    #pragma unroll
    for (int off = 1; off < 64; off <<= 1) {
        int y = __shfl_up(x, off, 64);
        if (lane >= off) x += y;
    }
    if (lane < nb) bs[lane] = x - v;           // exclusive block offset
    if (lane == nb - 1) {
        if (w == 0) row_di[N_DI] = x;
        else        row_mi[N_MI] = x;
    }
}

// Stage 3: add block offsets.
__global__ __launch_bounds__(256) void scan_add_kernel(const int* __restrict__ bsum,
                                                       int* __restrict__ row_di,
                                                       int* __restrict__ row_mi) {
    int* row; int n; const int* bs;
    if (blockIdx.y == 0) { row = row_di; n = N_DI; bs = bsum; }
    else                 { row = row_mi; n = N_MI; bs = bsum + 64; }
    int nb = (n + SCAN_CHUNK - 1) / SCAN_CHUNK;
    int b = blockIdx.x;
    if (b >= nb || b == 0) return;             // block 0 offset is 0
    int off = bs[b];
    int base = b * SCAN_CHUNK + threadIdx.x;
    #pragma unroll
    for (int e = 0; e < 8; ++e) {
        int i = base + e * 256;
        if (i < n) row[i] += off;
    }
}

__global__ void fill_kernel(const int* __restrict__ src, const int* __restrict__ dst,
                            const int* __restrict__ row_mi, const int* __restrict__ row_di,
                            int* cur_mi, int* cur_di, int* csr_mi, int* csr_di, int E) {
    int i = blockIdx.x * blockDim.x + threadIdx.x;
    if (i >= E) return;
    int s = src[i], d = dst[i];
    int p = atomicAdd(&cur_di[d], 1);
    csr_di[row_di[d] + p] = s;
    int q = atomicAdd(&cur_mi[s], 1);
    csr_mi[row_mi[s] + q] = d;
}

// ---------------------------------------------------------------------------
// Fragment-linear layout for an [Mpad x K] operand (K = KI*32):
//   chunk c (8 halves): lane=c&63 (lr=lane&15 -> row-in-16, q=lane>>4 -> ksub),
//   i=(c>>6)&3 (16-row group), k=(c>>8)%KI, mt=(c>>8)/KI (64-row tile).
//   element: row = mt*64+i*16+lr, col = k*32+q*8+e.
// A wave frag load (i,k) = 64 consecutive chunks = 1 KB contiguous.
// ---------------------------------------------------------------------------

// fp32 W [N x K] -> frag-linear fp16 (N-panels of 64)
struct CvtW {
    const float* s[14];
    _Float16* d[14];
    int K[14];
    int KI[14];
    int nch[14];
};

__global__ void cvtw_kernel(CvtW a) {
    int arr = blockIdx.y;
    int c = blockIdx.x * blockDim.x + threadIdx.x;
    if (c >= a.nch[arr]) return;
    int K = a.K[arr], KI = a.KI[arr];
    int lane = c & 63;
    int j = (c >> 6) & 3;
    int rest = c >> 8;
    int k = rest % KI;
    int p = rest / KI;
    int row = p * 64 + j * 16 + (lane & 15);
    int kcol = k * 32 + (lane >> 4) * 8;
    const float* s = a.s[arr] + (long)row * K + kcol;
    float4 u = *(const float4*)s;
    float4 v = *(const float4*)(s + 4);
    half8 h = {(_Float16)u.x, (_Float16)u.y, (_Float16)u.z, (_Float16)u.w,
               (_Float16)v.x, (_Float16)v.y, (_Float16)v.z, (_Float16)v.w};
    *(half8*)(a.d[arr] + (long)c * 8) = h;
}

// fp32 row-major [M x K] -> frag-linear fp16, LDS transpose, both sides stream.
template<int K>
__global__ __launch_bounds__(256) void cvt_frag(const float* __restrict__ in,
                                                _Float16* __restrict__ out, int M) {
    constexpr int KI = K / 32;
    constexpr int CPR = K / 8;              // chunks per row
    __shared__ _Float16 lds[64 * (K + 8)];
    const int tile = blockIdx.x;
    const int tid = threadIdx.x;
    // phase 1: contiguous read (+clamp), convert, padded LDS write
    #pragma unroll
    for (int it = 0; it < KI; ++it) {
        int c = tid + it * 256;             // 0 .. 8K-1
        int r = c / CPR, col = c % CPR;
        int row = tile * 64 + r;
        if (row >= M) row = M - 1;
        const float* g = in + (long)row * K + col * 8;
        float4 u = *(const float4*)g;
        float4 v = *(const float4*)(g + 4);
        half8 h = {(_Float16)u.x, (_Float16)u.y, (_Float16)u.z, (_Float16)u.w,
                   (_Float16)v.x, (_Float16)v.y, (_Float16)v.z, (_Float16)v.w};
        *(half8*)&lds[r * (K + 8) + col * 8] = h;
    }
    __syncthreads();
    // phase 2: frag-order LDS read (2-way free), contiguous global write
    #pragma unroll
    for (int it = 0; it < KI; ++it) {
        int c = tid + it * 256;
        int lane = c & 63, i = (c >> 6) & 3, k = c >> 8;
        half8 h = *(const half8*)&lds[(i * 16 + (lane & 15)) * (K + 8) + k * 32 + (lane >> 4) * 8];
        *(half8*)(out + ((long)tile * 8 * K + c) * 8) = h;
    }
}

// fp16 row-major [Mpad x K] -> frag-linear fp16 (same transpose, fp16 in)
template<int K>
__global__ __launch_bounds__(256) void repack(const _Float16* __restrict__ in,
                                              _Float16* __restrict__ out) {
    constexpr int KI = K / 32;
    constexpr int CPR = K / 8;
    __shared__ _Float16 lds[64 * (K + 8)];
    const int tile = blockIdx.x;
    const int tid = threadIdx.x;
    #pragma unroll
    for (int it = 0; it < KI; ++it) {
        int c = tid + it * 256;
        int r = c / CPR, col = c % CPR;
        half8 h = *(const half8*)(in + (long)tile * 64 * K + c * 8);
        *(half8*)&lds[r * (K + 8) + col * 8] = h;
    }
    __syncthreads();
    #pragma unroll
    for (int it = 0; it < KI; ++it) {
        int c = tid + it * 256;
        int lane = c & 63, i = (c >> 6) & 3, k = c >> 8;
        half8 h = *(const half8*)&lds[(i * 16 + (lane & 15)) * (K + 8) + k * 32 + (lane >> 4) * 8];
        *(half8*)(out + ((long)tile * 8 * K + c) * 8) = h;
    }
}

// ---------------------------------------------------------------------------
// Mean aggregation: one node per wave; reads row-major h, WRITES FRAG-LINEAR.
// ---------------------------------------------------------------------------
template<int DIN>
__global__ __launch_bounds__(256) void agg2_kernel(const _Float16* __restrict__ hsrc,
                                                   const int* __restrict__ row,
                                                   const int* __restrict__ csr,
                                                   _Float16* __restrict__ outf, int n) {
    constexpr int LPR = DIN / 8;
    constexpr int GR  = 64 / LPR;
    constexpr int KI  = DIN / 32;
    int node = blockIdx.x * 4 + (threadIdx.x >> 6);
    if (node >= n) return;
    int lane = threadIdx.x & 63;
    int g = lane / LPR, c = lane % LPR;
    int beg = row[node], end = row[node + 1];
    float acc[8] = {};
    #pragma unroll 2
    for (int j = beg + g; j < end; j += GR) {
        half8 v = *(const half8*)(hsrc + (long)csr[j] * DIN + c * 8);
        #pragma unroll
        for (int e = 0; e < 8; ++e) acc[e] += (float)v[e];
    }
    float inv = 1.f / (float)max(end - beg, 1);
    half8 o;
    #pragma unroll
    for (int e = 0; e < 8; ++e) {
        float s = acc[e];
        s += __shfl_down(s, 32);
        if (GR == 4) s += __shfl_down(s, 16);
        o[e] = (_Float16)(s * inv);
    }
    if (g == 0) {
        int mt = node >> 6, ii = (node >> 4) & 3, lrm = node & 15;
        long off = (((long)mt * KI + (c >> 2)) * 4 + ii) * 512 + (lrm + 16 * (c & 3)) * 8;
        *(half8*)(outf + off) = o;
    }
}

// ---------------------------------------------------------------------------
// Fragment-linear fp16 MFMA GEMM: all loads are contiguous 1-KB wave streams.
// Block = 4 waves, each one 64x64 tile stacked along M. No LDS, no barriers.
// C = act(A1@W1^T [+ A2@W2^T] + bias [+ Cadd_f32]); grid (Mpad/256, N/64).
// ---------------------------------------------------------------------------
template<int KI, bool DUAL>
__global__ __launch_bounds__(256, 3) void hgemm_f(
    const _Float16* __restrict__ A1f, const _Float16* __restrict__ W1f,
    const _Float16* __restrict__ A2f, const _Float16* __restrict__ W2f,
    const float* __restrict__ bias, const float* __restrict__ Cadd,
    _Float16* __restrict__ C, int M, int N, int relu)
{
    const int wave = threadIdx.x >> 6, lane = threadIdx.x & 63;
    const int quad = lane >> 4, lr = lane & 15;
    const int mt = blockIdx.x * 4 + wave;   // 64-row tile
    const int p = blockIdx.y;               // 64-col panel
    const long abase = ((long)mt * KI * 4) * 512 + lane * 8;
    const long wbase = ((long)p  * KI * 4) * 512 + lane * 8;

    floatx4 acc[4][4] = {};

    #pragma unroll
    for (int pass = 0; pass < (DUAL ? 2 : 1); ++pass) {
        const _Float16* A = pass ? A2f : A1f;
        const _Float16* W = pass ? W2f : W1f;
        #pragma unroll
        for (int k = 0; k < KI; ++k) {
            half8 af[4], bf[4];
            #pragma unroll
            for (int i = 0; i < 4; ++i)
                af[i] = *(const half8*)(A + abase + (k * 4 + i) * 512);
            #pragma unroll
            for (int j = 0; j < 4; ++j)
                bf[j] = *(const half8*)(W + wbase + (k * 4 + j) * 512);
            #pragma unroll
            for (int i = 0; i < 4; ++i)
                #pragma unroll
                for (int j = 0; j < 4; ++j)
                    acc[i][j] = __builtin_amdgcn_mfma_f32_16x16x32_f16(af[i], bf[j], acc[i][j], 0, 0, 0);
        }
    }

    // epilogue: C/D layout col(lane&15)=n, row(quad*4+r)=m
    const int m0 = mt * 64, n0 = p * 64;
    #pragma unroll
    for (int i = 0; i < 4; ++i) {
        int mb = m0 + i * 16 + quad * 4;
        #pragma unroll
        for (int j = 0; j < 4; ++j) {
            int n = n0 + j * 16 + lr;
            float bn = bias[n];
            #pragma unroll
            for (int r = 0; r < 4; ++r) {
                int m = mb + r;
                if (m < M) {
                    float v = acc[i][j][r] + bn;
                    if (Cadd) v += Cadd[(long)m * N + n];
                    if (relu) v = fmaxf(v, 0.f);
                    C[(long)m * N + n] = (_Float16)v;
                }
            }
        }
    }
}

// ---------------------------------------------------------------------------
// Classifier: out[e] = dot64(h_mi[ls[e]], h_di[ld[e]]), fp16 in, fp32 out
// ---------------------------------------------------------------------------
__global__ void classify_kernel(const _Float16* __restrict__ hmi, const _Float16* __restrict__ hdi,
                                const int* __restrict__ ls, const int* __restrict__ ld,
                                float* __restrict__ out, int L) {
    long idx = (long)blockIdx.x * blockDim.x + threadIdx.x;
    int e = (int)(idx >> 4), q = (int)(idx & 15);
    if (e >= L) return;
    const half4* ra = (const half4*)(hmi + (long)ls[e] * 64);
    const half4* rb = (const half4*)(hdi + (long)ld[e] * 64);
    half4 a = ra[q], b = rb[q];
    float s = (float)a.x * (float)b.x + (float)a.y * (float)b.y +
              (float)a.z * (float)b.z + (float)a.w * (float)b.w;
    #pragma unroll
    for (int off = 8; off >= 1; off >>= 1) s += __shfl_down(s, off, 16);
    if (q == 0) out[e] = s;
}

// ---------------------------------------------------------------------------
// Launch
// ---------------------------------------------------------------------------
extern "C" void kernel_launch(void* const* d_in, const int* in_sizes, int n_in,
                              void* d_out, int out_size, void* d_ws, size_t ws_size,
                              hipStream_t stream) {
    const float* x_mi   = (const float*)d_in[0];
    const float* x_di   = (const float*)d_in[1];
    const float* W_mi   = (const float*)d_in[2];
    const float* b_mi   = (const float*)d_in[3];
    const float* W_di   = (const float*)d_in[4];
    const float* b_di   = (const float*)d_in[5];
    const float* emb_mi = (const float*)d_in[6];
    const float* emb_di = (const float*)d_in[7];
    const float* Wl1_md = (const float*)d_in[8];
    const float* bl1_md = (const float*)d_in[9];
    const float* Wr1_md = (const float*)d_in[10];
    const float* Wl1_dm = (const float*)d_in[11];
    const float* bl1_dm = (const float*)d_in[12];
    const float* Wr1_dm = (const float*)d_in[13];
    const float* Wl2_md = (const float*)d_in[14];
    const float* bl2_md = (const float*)d_in[15];
    const float* Wr2_md = (const float*)d_in[16];
    const float* Wl2_dm = (const float*)d_in[17];
    const float* bl2_dm = (const float*)d_in[18];
    const float* Wr2_dm = (const float*)d_in[19];
    const float* Wl3_md = (const float*)d_in[20];
    const float* bl3_md = (const float*)d_in[21];
    const float* Wr3_md = (const float*)d_in[22];
    const float* Wl3_dm = (const float*)d_in[23];
    const float* bl3_dm = (const float*)d_in[24];
    const float* Wr3_dm = (const float*)d_in[25];
    const int* edge_src  = (const int*)d_in[26];
    const int* edge_dst  = (const int*)d_in[27];
    const int* label_src = (const int*)d_in[28];
    const int* label_dst = (const int*)d_in[29];
    const int E = in_sizes[26];
    const int L = in_sizes[28];
    float* out = (float*)d_out;

    // ---- workspace layout ----
    _Float16* hp = (_Float16*)d_ws;
    _Float16* wWmi  = hp; hp += 128 * 256;
    _Float16* wWdi  = hp; hp += 128 * 128;
    _Float16* wl1md = hp; hp += 256 * 128;
    _Float16* wr1md = hp; hp += 256 * 128;
    _Float16* wl1dm = hp; hp += 256 * 128;
    _Float16* wr1dm = hp; hp += 256 * 128;
    _Float16* wl2md = hp; hp += 128 * 256;
    _Float16* wr2md = hp; hp += 128 * 256;
    _Float16* wl2dm = hp; hp += 128 * 256;
    _Float16* wr2dm = hp; hp += 128 * 256;
    _Float16* wl3md = hp; hp += 64 * 128;
    _Float16* wr3md = hp; hp += 64 * 128;
    _Float16* wl3dm = hp; hp += 64 * 128;
    _Float16* wr3dm = hp; hp += 64 * 128;
    _Float16* h_mi0 = hp; hp += (long)MI_P * 256;   // row-major h (mi)
    _Float16* h_mi1 = hp; hp += (long)MI_P * 256;
    _Float16* h_di0 = hp; hp += (long)DI_P * 256;
    _Float16* h_di1 = hp; hp += (long)DI_P * 256;
    _Float16* hf_mi = hp; hp += (long)MI_P * 256;   // frag-linear root copy / init x
    _Float16* hf_di = hp; hp += (long)DI_P * 256;
    _Float16* agghf = hp; hp += (long)MI_P * 256;   // frag-linear agg output

    int* ip = (int*)hp;
    int* deg_di = ip;  ip += N_DI;
    int* deg_mi = ip;  ip += N_MI;
    int* cur_di = ip;  ip += N_DI;
    int* cur_mi = ip;  ip += N_MI;
    int* row_di = ip;  ip += N_DI + 1;
    int* row_mi = ip;  ip += N_MI + 1;
    int* csr_di = ip;  ip += E;
    int* csr_mi = ip;  ip += E;
    int* bsum   = ip;  ip += 128;

    // ---- CSR build ----
    hipMemsetAsync(deg_di, 0, (size_t)(2 * (N_DI + N_MI)) * sizeof(int), stream);
    int eb = (E + 255) / 256;
    count_kernel<<<eb, 256, 0, stream>>>(edge_src, edge_dst, deg_mi, deg_di, E);
    scan_part_kernel<<<dim3(NB_MI, 2), 256, 0, stream>>>(deg_di, deg_mi, row_di, row_mi, bsum);
    scan_sums_kernel<<<1, 128, 0, stream>>>(bsum, row_di, row_mi);
    scan_add_kernel<<<dim3(NB_MI, 2), 256, 0, stream>>>(bsum, row_di, row_mi);
    fill_kernel<<<eb, 256, 0, stream>>>(edge_src, edge_dst, row_mi, row_di,
                                        cur_mi, cur_di, csr_mi, csr_di, E);

    // ---- W converts -> frag-linear fp16 ----
    CvtW cw;
    const float* srcs[14] = {W_mi, W_di, Wl1_md, Wr1_md, Wl1_dm, Wr1_dm,
                             Wl2_md, Wr2_md, Wl2_dm, Wr2_dm, Wl3_md, Wr3_md, Wl3_dm, Wr3_dm};
    _Float16* dsts[14] = {wWmi, wWdi, wl1md, wr1md, wl1dm, wr1dm,
                          wl2md, wr2md, wl2dm, wr2dm, wl3md, wr3md, wl3dm, wr3dm};
    int Ks[14]  = {256, 128, 128, 128, 128, 128, 256, 256, 256, 256, 128, 128, 128, 128};
    int Ns[14]  = {128, 128, 256, 256, 256, 256, 128, 128, 128, 128, 64, 64, 64, 64};
    for (int i = 0; i < 14; ++i) {
        cw.s[i] = srcs[i]; cw.d[i] = dsts[i];
        cw.K[i] = Ks[i]; cw.KI[i] = Ks[i] / 32;
        cw.nch[i] = Ns[i] * Ks[i] / 8;
    }
    cvtw_kernel<<<dim3(16, 14), 256, 0, stream>>>(cw);

    // ---- x -> frag-linear fp16 (aliased into hf buffers) ----
    cvt_frag<256><<<MI_P / 64, 256, 0, stream>>>(x_mi, hf_mi, N_MI);
    cvt_frag<128><<<DI_P / 64, 256, 0, stream>>>(x_di, hf_di, N_DI);

    // ---- init: h0 = x @ W^T + b + emb ----
    hgemm_f<8, false><<<dim3(MI_P / 256, 2), 256, 0, stream>>>(
        hf_mi, wWmi, nullptr, nullptr, b_mi, emb_mi, h_mi0, N_MI, 128, 0);
    hgemm_f<4, false><<<dim3(DI_P / 256, 2), 256, 0, stream>>>(
        hf_di, wWdi, nullptr, nullptr, b_di, emb_di, h_di0, N_DI, 128, 0);

    // ---- Layer 1: 128 -> 256, relu ----
    repack<128><<<MI_P / 64, 256, 0, stream>>>(h_mi0, hf_mi);
    repack<128><<<DI_P / 64, 256, 0, stream>>>(h_di0, hf_di);
    agg2_kernel<128><<<(N_DI + 3) / 4, 256, 0, stream>>>(h_mi0, row_di, csr_di, agghf, N_DI);
    hgemm_f<4, true><<<dim3(DI_P / 256, 4), 256, 0, stream>>>(
        agghf, wl1md, hf_di, wr1md, bl1_md, nullptr, h_di1, N_DI, 256, 1);
    agg2_kernel<128><<<(N_MI + 3) / 4, 256, 0, stream>>>(h_di0, row_mi, csr_mi, agghf, N_MI);
    hgemm_f<4, true><<<dim3(MI_P / 256, 4), 256, 0, stream>>>(
        agghf, wl1dm, hf_mi, wr1dm, bl1_dm, nullptr, h_mi1, N_MI, 256, 1);

    // ---- Layer 2: 256 -> 128, relu ----
    repack<256><<<MI_P / 64, 256, 0, stream>>>(h_mi1, hf_mi);
    repack<256><<<DI_P / 64, 256, 0, stream>>>(h_di1, hf_di);
    agg2_kernel<256><<<(N_DI + 3) / 4, 256, 0, stream>>>(h_mi1, row_di, csr_di, agghf, N_DI);
    hgemm_f<8, true><<<dim3(DI_P / 256, 2), 256, 0, stream>>>(
        agghf, wl2md, hf_di, wr2md, bl2_md, nullptr, h_di0, N_DI, 128, 1);
    agg2_kernel<256><<<(N_MI + 3) / 4, 256, 0, stream>>>(h_di1, row_mi, csr_mi, agghf, N_MI);
    hgemm_f<8, true><<<dim3(MI_P / 256, 2), 256, 0, stream>>>(
        agghf, wl2dm, hf_mi, wr2dm, bl2_dm, nullptr, h_mi0, N_MI, 128, 1);

    // ---- Layer 3: 128 -> 64, no relu ----
    repack<128><<<MI_P / 64, 256, 0, stream>>>(h_mi0, hf_mi);
    repack<128><<<DI_P / 64, 256, 0, stream>>>(h_di0, hf_di);
    agg2_kernel<128><<<(N_DI + 3) / 4, 256, 0, stream>>>(h_mi0, row_di, csr_di, agghf, N_DI);
    hgemm_f<4, true><<<dim3(DI_P / 256, 1), 256, 0, stream>>>(
        agghf, wl3md, hf_di, wr3md, bl3_md, nullptr, h_di1, N_DI, 64, 0);
    agg2_kernel<128><<<(N_MI + 3) / 4, 256, 0, stream>>>(h_di0, row_mi, csr_mi, agghf, N_MI);
    hgemm_f<4, true><<<dim3(MI_P / 256, 1), 256, 0, stream>>>(
        agghf, wl3dm, hf_mi, wr3dm, bl3_dm, nullptr, h_mi1, N_MI, 64, 0);

    // ---- classifier ----
    classify_kernel<<<((long)L * 16 + 255) / 256, 256, 0, stream>>>(
        h_mi1, h_di1, label_src, label_dst, out, L);
}

// Round 3
// 827.250 us; speedup vs baseline: 1.1719x; 1.0792x over previous
//
#include <hip/hip_runtime.h>

#define N_MI 100000
#define N_DI 50000
#define MI_P 100352   // multiple of 256
#define DI_P 50176    // multiple of 256

#define SCAN_CHUNK 2048
#define NB_DI ((N_DI + SCAN_CHUNK - 1) / SCAN_CHUNK)   // 25
#define NB_MI ((N_MI + SCAN_CHUNK - 1) / SCAN_CHUNK)   // 49

typedef _Float16 half8  __attribute__((ext_vector_type(8)));
typedef _Float16 half4  __attribute__((ext_vector_type(4)));
typedef float    floatx4 __attribute__((ext_vector_type(4)));

// ---------------------------------------------------------------------------
// CSR build
// ---------------------------------------------------------------------------
__global__ void count_kernel(const int* __restrict__ src, const int* __restrict__ dst,
                             int* deg_mi, int* deg_di, int E) {
    int i = blockIdx.x * blockDim.x + threadIdx.x;
    if (i < E) {
        atomicAdd(&deg_mi[src[i]], 1);
        atomicAdd(&deg_di[dst[i]], 1);
    }
}

// Hierarchical scan, stage 1: each block scans a 2048-element chunk.
__global__ __launch_bounds__(256) void scan_part_kernel(const int* __restrict__ deg_di,
                                                        const int* __restrict__ deg_mi,
                                                        int* __restrict__ row_di,
                                                        int* __restrict__ row_mi,
                                                        int* __restrict__ bsum) {
    const int* deg; int* row; int n; int* bs;
    if (blockIdx.y == 0) { deg = deg_di; row = row_di; n = N_DI; bs = bsum; }
    else                 { deg = deg_mi; row = row_mi; n = N_MI; bs = bsum + 64; }
    int nb = (n + SCAN_CHUNK - 1) / SCAN_CHUNK;
    if ((int)blockIdx.x >= nb) return;
    int t = threadIdx.x;
    int base = blockIdx.x * SCAN_CHUNK + t * 8;
    int v[8]; int s = 0;
    #pragma unroll
    for (int e = 0; e < 8; ++e) {
        int i = base + e;
        v[e] = (i < n) ? deg[i] : 0;
        s += v[e];
    }
    int lane = t & 63, w = t >> 6;
    int x = s;
    #pragma unroll
    for (int off = 1; off < 64; off <<= 1) {
        int y = __shfl_up(x, off, 64);
        if (lane >= off) x += y;
    }
    __shared__ int wsum[4];
    if (lane == 63) wsum[w] = x;
    __syncthreads();
    int woff = 0;
    #pragma unroll
    for (int i = 0; i < 3; ++i) if (i < w) woff += wsum[i];
    int run = woff + x - s;
    #pragma unroll
    for (int e = 0; e < 8; ++e) {
        int i = base + e;
        if (i < n) row[i] = run;
        run += v[e];
    }
    if (t == 255) bs[blockIdx.x] = woff + x;
}

// Stage 2: scan the per-block sums. Wave 0 -> di, wave 1 -> mi.
__global__ void scan_sums_kernel(int* __restrict__ bsum, int* __restrict__ row_di,
                                 int* __restrict__ row_mi) {
    int w = threadIdx.x >> 6, lane = threadIdx.x & 63;
    int nb = (w == 0) ? NB_DI : NB_MI;
    int* bs = bsum + w * 64;
    int v = (lane < nb) ? bs[lane] : 0;
    int x = v;
    #pragma unroll
    for (int off = 1; off < 64; off <<= 1) {
        int y = __shfl_up(x, off, 64);
        if (lane >= off) x += y;
    }
    if (lane < nb) bs[lane] = x - v;
    if (lane == nb - 1) {
        if (w == 0) row_di[N_DI] = x;
        else        row_mi[N_MI] = x;
    }
}

// Stage 3: add block offsets.
__global__ __launch_bounds__(256) void scan_add_kernel(const int* __restrict__ bsum,
                                                       int* __restrict__ row_di,
                                                       int* __restrict__ row_mi) {
    int* row; int n; const int* bs;
    if (blockIdx.y == 0) { row = row_di; n = N_DI; bs = bsum; }
    else                 { row = row_mi; n = N_MI; bs = bsum + 64; }
    int nb = (n + SCAN_CHUNK - 1) / SCAN_CHUNK;
    int b = blockIdx.x;
    if (b >= nb || b == 0) return;
    int off = bs[b];
    int base = b * SCAN_CHUNK + threadIdx.x;
    #pragma unroll
    for (int e = 0; e < 8; ++e) {
        int i = base + e * 256;
        if (i < n) row[i] += off;
    }
}

__global__ void fill_kernel(const int* __restrict__ src, const int* __restrict__ dst,
                            const int* __restrict__ row_mi, const int* __restrict__ row_di,
                            int* cur_mi, int* cur_di, int* csr_mi, int* csr_di, int E) {
    int i = blockIdx.x * blockDim.x + threadIdx.x;
    if (i >= E) return;
    int s = src[i], d = dst[i];
    int p = atomicAdd(&cur_di[d], 1);
    csr_di[row_di[d] + p] = s;
    int q = atomicAdd(&cur_mi[s], 1);
    csr_mi[row_mi[s] + q] = d;
}

// ---------------------------------------------------------------------------
// Fragment-linear layout for an [Mpad x K] operand (K = KI*32):
//   chunk c (8 halves): lane=c&63 (lr=lane&15 -> row-in-16, q=lane>>4 -> ksub),
//   i=(c>>6)&3 (16-row group), k=(c>>8)%KI, mt=(c>>8)/KI (64-row tile).
//   element: row = mt*64+i*16+lr, col = k*32+q*8+e.
// ---------------------------------------------------------------------------

// fp32 W [N x K] -> frag-linear fp16 (N-panels of 64)
struct CvtW {
    const float* s[14];
    _Float16* d[14];
    int K[14];
    int KI[14];
    int nch[14];
};

__global__ void cvtw_kernel(CvtW a) {
    int arr = blockIdx.y;
    int c = blockIdx.x * blockDim.x + threadIdx.x;
    if (c >= a.nch[arr]) return;
    int K = a.K[arr], KI = a.KI[arr];
    int lane = c & 63;
    int j = (c >> 6) & 3;
    int rest = c >> 8;
    int k = rest % KI;
    int p = rest / KI;
    int row = p * 64 + j * 16 + (lane & 15);
    int kcol = k * 32 + (lane >> 4) * 8;
    const float* s = a.s[arr] + (long)row * K + kcol;
    float4 u = *(const float4*)s;
    float4 v = *(const float4*)(s + 4);
    half8 h = {(_Float16)u.x, (_Float16)u.y, (_Float16)u.z, (_Float16)u.w,
               (_Float16)v.x, (_Float16)v.y, (_Float16)v.z, (_Float16)v.w};
    *(half8*)(a.d[arr] + (long)c * 8) = h;
}

// fp32 row-major [M x K] -> frag-linear fp16, LDS transpose.
template<int K>
__global__ __launch_bounds__(256) void cvt_frag(const float* __restrict__ in,
                                                _Float16* __restrict__ out, int M) {
    constexpr int KI = K / 32;
    constexpr int CPR = K / 8;
    __shared__ _Float16 lds[64 * (K + 8)];
    const int tile = blockIdx.x;
    const int tid = threadIdx.x;
    #pragma unroll
    for (int it = 0; it < KI; ++it) {
        int c = tid + it * 256;
        int r = c / CPR, col = c % CPR;
        int row = tile * 64 + r;
        if (row >= M) row = M - 1;
        const float* g = in + (long)row * K + col * 8;
        float4 u = *(const float4*)g;
        float4 v = *(const float4*)(g + 4);
        half8 h = {(_Float16)u.x, (_Float16)u.y, (_Float16)u.z, (_Float16)u.w,
                   (_Float16)v.x, (_Float16)v.y, (_Float16)v.z, (_Float16)v.w};
        *(half8*)&lds[r * (K + 8) + col * 8] = h;
    }
    __syncthreads();
    #pragma unroll
    for (int it = 0; it < KI; ++it) {
        int c = tid + it * 256;
        int lane = c & 63, i = (c >> 6) & 3, k = c >> 8;
        half8 h = *(const half8*)&lds[(i * 16 + (lane & 15)) * (K + 8) + k * 32 + (lane >> 4) * 8];
        *(half8*)(out + ((long)tile * 8 * K + c) * 8) = h;
    }
}

// ---------------------------------------------------------------------------
// Mean aggregation: one node per wave; reads row-major h, WRITES FRAG-LINEAR.
// ---------------------------------------------------------------------------
template<int DIN>
__global__ __launch_bounds__(256) void agg2_kernel(const _Float16* __restrict__ hsrc,
                                                   const int* __restrict__ row,
                                                   const int* __restrict__ csr,
                                                   _Float16* __restrict__ outf, int n) {
    constexpr int LPR = DIN / 8;
    constexpr int GR  = 64 / LPR;
    constexpr int KI  = DIN / 32;
    int node = blockIdx.x * 4 + (threadIdx.x >> 6);
    if (node >= n) return;
    int lane = threadIdx.x & 63;
    int g = lane / LPR, c = lane % LPR;
    int beg = row[node], end = row[node + 1];
    float acc[8] = {};
    #pragma unroll 2
    for (int j = beg + g; j < end; j += GR) {
        half8 v = *(const half8*)(hsrc + (long)csr[j] * DIN + c * 8);
        #pragma unroll
        for (int e = 0; e < 8; ++e) acc[e] += (float)v[e];
    }
    float inv = 1.f / (float)max(end - beg, 1);
    half8 o;
    #pragma unroll
    for (int e = 0; e < 8; ++e) {
        float s = acc[e];
        s += __shfl_down(s, 32);
        if (GR == 4) s += __shfl_down(s, 16);
        o[e] = (_Float16)(s * inv);
    }
    if (g == 0) {
        int mt = node >> 6, ii = (node >> 4) & 3, lrm = node & 15;
        long off = (((long)mt * KI + (c >> 2)) * 4 + ii) * 512 + (lrm + 16 * (c & 3)) * 8;
        *(half8*)(outf + off) = o;
    }
}

// ---------------------------------------------------------------------------
// Fragment-linear fp16 MFMA GEMM.
// Wave tile = (MR*16) x 64; block = 4 waves stacked along M; grid
// (Mpad/(64*MR), N/64).  Epilogue stages the fp16 tile in per-wave LDS, then
//   - vectorized row-major store to C (8 rows x 8 half8-chunks per pass)
//   - optional frag-linear store to Cf (feeds the next GEMM's A operand)
// C = act(A1@W1^T [+ A2@W2^T] + bias [+ Cadd_f32]).
// ---------------------------------------------------------------------------
template<int KI, bool DUAL, int MR>
__global__ __launch_bounds__(256, 4) void hgemm_f(
    const _Float16* __restrict__ A1f, const _Float16* __restrict__ W1f,
    const _Float16* __restrict__ A2f, const _Float16* __restrict__ W2f,
    const float* __restrict__ bias, const float* __restrict__ Cadd,
    _Float16* __restrict__ C, _Float16* __restrict__ Cf, int M, int N, int relu)
{
    const int wave = threadIdx.x >> 6, lane = threadIdx.x & 63;
    const int quad = lane >> 4, lr = lane & 15;
    const int g0 = (blockIdx.x * 4 + wave) * MR;   // first 16-row group (global)
    const int mt = g0 >> 2, i0 = g0 & 3;           // 64-row frag tile, group-in-tile
    const int p = blockIdx.y;                      // 64-col panel
    const long abase = ((long)(mt * KI * 4 + i0)) * 512 + lane * 8;
    const long wbase = ((long)p * KI * 4) * 512 + lane * 8;

    __shared__ _Float16 lds[4][MR * 16 * 72];      // 72-half stride: conflict-safe
    _Float16* lw = lds[wave];

    floatx4 acc[MR][4] = {};

    #pragma unroll
    for (int pass = 0; pass < (DUAL ? 2 : 1); ++pass) {
        const _Float16* A = pass ? A2f : A1f;
        const _Float16* W = pass ? W2f : W1f;
        #pragma unroll
        for (int k = 0; k < KI; ++k) {
            half8 af[MR], bf[4];
            #pragma unroll
            for (int i = 0; i < MR; ++i)
                af[i] = *(const half8*)(A + abase + (k * 4 + i) * 512);
            #pragma unroll
            for (int j = 0; j < 4; ++j)
                bf[j] = *(const half8*)(W + wbase + (k * 4 + j) * 512);
            #pragma unroll
            for (int i = 0; i < MR; ++i)
                #pragma unroll
                for (int j = 0; j < 4; ++j)
                    acc[i][j] = __builtin_amdgcn_mfma_f32_16x16x32_f16(af[i], bf[j], acc[i][j], 0, 0, 0);
        }
    }

    // ---- compute + stage fp16 tile in LDS (C/D layout: col=lr, row=quad*4+r)
    const int m0 = g0 * 16, n0 = p * 64;
    #pragma unroll
    for (int ii = 0; ii < MR; ++ii) {
        #pragma unroll
        for (int j = 0; j < 4; ++j) {
            int n = n0 + j * 16 + lr;
            float bn = bias[n];
            #pragma unroll
            for (int r = 0; r < 4; ++r) {
                int m = m0 + ii * 16 + quad * 4 + r;
                float v = acc[ii][j][r] + bn;
                if (Cadd && m < M) v += Cadd[(long)m * N + n];
                if (relu) v = fmaxf(v, 0.f);
                lw[(ii * 16 + quad * 4 + r) * 72 + j * 16 + lr] = (_Float16)v;
            }
        }
    }
    __syncthreads();

    // ---- row-major store: 8 lanes x half8 (8 halves) cover one 64-col row;
    //      64 lanes = 8 rows per pass, MR*2 passes cover MR*16 rows.
    const int r2 = lane >> 3, cs = lane & 7;
    #pragma unroll
    for (int ii = 0; ii < MR * 2; ++ii) {
        int m = m0 + ii * 8 + r2;
        if (m < M)
            *(half8*)(C + (long)m * N + n0 + cs * 8) =
                *(const half8*)&lw[(ii * 8 + r2) * 72 + cs * 8];
    }

    // ---- frag-linear store (A-operand layout for the next GEMM)
    if (Cf) {
        const int KIn = N >> 5;
        #pragma unroll
        for (int ii = 0; ii < MR; ++ii) {
            #pragma unroll
            for (int k2 = 0; k2 < 2; ++k2) {
                half8 h = *(const half8*)&lw[(ii * 16 + lr) * 72 + k2 * 32 + quad * 8];
                *(half8*)(Cf + ((long)(mt * KIn + p * 2 + k2) * 4 + i0 + ii) * 512 + lane * 8) = h;
            }
        }
    }
}

// ---------------------------------------------------------------------------
// Classifier: out[e] = dot64(h_mi[ls[e]], h_di[ld[e]]), fp16 in, fp32 out
// ---------------------------------------------------------------------------
__global__ void classify_kernel(const _Float16* __restrict__ hmi, const _Float16* __restrict__ hdi,
                                const int* __restrict__ ls, const int* __restrict__ ld,
                                float* __restrict__ out, int L) {
    long idx = (long)blockIdx.x * blockDim.x + threadIdx.x;
    int e = (int)(idx >> 4), q = (int)(idx & 15);
    if (e >= L) return;
    const half4* ra = (const half4*)(hmi + (long)ls[e] * 64);
    const half4* rb = (const half4*)(hdi + (long)ld[e] * 64);
    half4 a = ra[q], b = rb[q];
    float s = (float)a.x * (float)b.x + (float)a.y * (float)b.y +
              (float)a.z * (float)b.z + (float)a.w * (float)b.w;
    #pragma unroll
    for (int off = 8; off >= 1; off >>= 1) s += __shfl_down(s, off, 16);
    if (q == 0) out[e] = s;
}

// ---------------------------------------------------------------------------
// Launch
// ---------------------------------------------------------------------------
extern "C" void kernel_launch(void* const* d_in, const int* in_sizes, int n_in,
                              void* d_out, int out_size, void* d_ws, size_t ws_size,
                              hipStream_t stream) {
    const float* x_mi   = (const float*)d_in[0];
    const float* x_di   = (const float*)d_in[1];
    const float* W_mi   = (const float*)d_in[2];
    const float* b_mi   = (const float*)d_in[3];
    const float* W_di   = (const float*)d_in[4];
    const float* b_di   = (const float*)d_in[5];
    const float* emb_mi = (const float*)d_in[6];
    const float* emb_di = (const float*)d_in[7];
    const float* Wl1_md = (const float*)d_in[8];
    const float* bl1_md = (const float*)d_in[9];
    const float* Wr1_md = (const float*)d_in[10];
    const float* Wl1_dm = (const float*)d_in[11];
    const float* bl1_dm = (const float*)d_in[12];
    const float* Wr1_dm = (const float*)d_in[13];
    const float* Wl2_md = (const float*)d_in[14];
    const float* bl2_md = (const float*)d_in[15];
    const float* Wr2_md = (const float*)d_in[16];
    const float* Wl2_dm = (const float*)d_in[17];
    const float* bl2_dm = (const float*)d_in[18];
    const float* Wr2_dm = (const float*)d_in[19];
    const float* Wl3_md = (const float*)d_in[20];
    const float* bl3_md = (const float*)d_in[21];
    const float* Wr3_md = (const float*)d_in[22];
    const float* Wl3_dm = (const float*)d_in[23];
    const float* bl3_dm = (const float*)d_in[24];
    const float* Wr3_dm = (const float*)d_in[25];
    const int* edge_src  = (const int*)d_in[26];
    const int* edge_dst  = (const int*)d_in[27];
    const int* label_src = (const int*)d_in[28];
    const int* label_dst = (const int*)d_in[29];
    const int E = in_sizes[26];
    const int L = in_sizes[28];
    float* out = (float*)d_out;

    // ---- workspace layout ----
    _Float16* hp = (_Float16*)d_ws;
    _Float16* wWmi  = hp; hp += 128 * 256;
    _Float16* wWdi  = hp; hp += 128 * 128;
    _Float16* wl1md = hp; hp += 256 * 128;
    _Float16* wr1md = hp; hp += 256 * 128;
    _Float16* wl1dm = hp; hp += 256 * 128;
    _Float16* wr1dm = hp; hp += 256 * 128;
    _Float16* wl2md = hp; hp += 128 * 256;
    _Float16* wr2md = hp; hp += 128 * 256;
    _Float16* wl2dm = hp; hp += 128 * 256;
    _Float16* wr2dm = hp; hp += 128 * 256;
    _Float16* wl3md = hp; hp += 64 * 128;
    _Float16* wr3md = hp; hp += 64 * 128;
    _Float16* wl3dm = hp; hp += 64 * 128;
    _Float16* wr3dm = hp; hp += 64 * 128;
    _Float16* h_mi0 = hp; hp += (long)MI_P * 128;   // row-major h (init/L2 out)
    _Float16* h_mi1 = hp; hp += (long)MI_P * 256;   // row-major h (L1/L3 out)
    _Float16* h_di0 = hp; hp += (long)DI_P * 128;
    _Float16* h_di1 = hp; hp += (long)DI_P * 256;
    _Float16* hfa_mi = hp; hp += (long)MI_P * 128;  // frag h (init/L2 out)
    _Float16* hfb_mi = hp; hp += (long)MI_P * 256;  // frag x / frag h (L1 out)
    _Float16* hfa_di = hp; hp += (long)DI_P * 128;
    _Float16* hfb_di = hp; hp += (long)DI_P * 256;
    _Float16* agghf  = hp; hp += (long)MI_P * 256;  // frag-linear agg output

    int* ip = (int*)hp;
    int* deg_di = ip;  ip += N_DI;
    int* deg_mi = ip;  ip += N_MI;
    int* cur_di = ip;  ip += N_DI;
    int* cur_mi = ip;  ip += N_MI;
    int* row_di = ip;  ip += N_DI + 1;
    int* row_mi = ip;  ip += N_MI + 1;
    int* csr_di = ip;  ip += E;
    int* csr_mi = ip;  ip += E;
    int* bsum   = ip;  ip += 128;

    // ---- CSR build ----
    hipMemsetAsync(deg_di, 0, (size_t)(2 * (N_DI + N_MI)) * sizeof(int), stream);
    int eb = (E + 255) / 256;
    count_kernel<<<eb, 256, 0, stream>>>(edge_src, edge_dst, deg_mi, deg_di, E);
    scan_part_kernel<<<dim3(NB_MI, 2), 256, 0, stream>>>(deg_di, deg_mi, row_di, row_mi, bsum);
    scan_sums_kernel<<<1, 128, 0, stream>>>(bsum, row_di, row_mi);
    scan_add_kernel<<<dim3(NB_MI, 2), 256, 0, stream>>>(bsum, row_di, row_mi);
    fill_kernel<<<eb, 256, 0, stream>>>(edge_src, edge_dst, row_mi, row_di,
                                        cur_mi, cur_di, csr_mi, csr_di, E);

    // ---- W converts -> frag-linear fp16 ----
    CvtW cw;
    const float* srcs[14] = {W_mi, W_di, Wl1_md, Wr1_md, Wl1_dm, Wr1_dm,
                             Wl2_md, Wr2_md, Wl2_dm, Wr2_dm, Wl3_md, Wr3_md, Wl3_dm, Wr3_dm};
    _Float16* dsts[14] = {wWmi, wWdi, wl1md, wr1md, wl1dm, wr1dm,
                          wl2md, wr2md, wl2dm, wr2dm, wl3md, wr3md, wl3dm, wr3dm};
    int Ks[14]  = {256, 128, 128, 128, 128, 128, 256, 256, 256, 256, 128, 128, 128, 128};
    int Ns[14]  = {128, 128, 256, 256, 256, 256, 128, 128, 128, 128, 64, 64, 64, 64};
    for (int i = 0; i < 14; ++i) {
        cw.s[i] = srcs[i]; cw.d[i] = dsts[i];
        cw.K[i] = Ks[i]; cw.KI[i] = Ks[i] / 32;
        cw.nch[i] = Ns[i] * Ks[i] / 8;
    }
    cvtw_kernel<<<dim3(16, 14), 256, 0, stream>>>(cw);

    // ---- x -> frag-linear fp16 (staged in the hfb ping buffers) ----
    cvt_frag<256><<<MI_P / 64, 256, 0, stream>>>(x_mi, hfb_mi, N_MI);
    cvt_frag<128><<<DI_P / 64, 256, 0, stream>>>(x_di, hfb_di, N_DI);

    // ---- init: h0 = x @ W^T + b + emb  (row-major + frag out) ----
    hgemm_f<8, false, 2><<<dim3(MI_P / 128, 2), 256, 0, stream>>>(
        hfb_mi, wWmi, nullptr, nullptr, b_mi, emb_mi, h_mi0, hfa_mi, N_MI, 128, 0);
    hgemm_f<4, false, 1><<<dim3(DI_P / 64, 2), 256, 0, stream>>>(
        hfb_di, wWdi, nullptr, nullptr, b_di, emb_di, h_di0, hfa_di, N_DI, 128, 0);

    // ---- Layer 1: 128 -> 256, relu ----
    agg2_kernel<128><<<(N_DI + 3) / 4, 256, 0, stream>>>(h_mi0, row_di, csr_di, agghf, N_DI);
    hgemm_f<4, true, 1><<<dim3(DI_P / 64, 4), 256, 0, stream>>>(
        agghf, wl1md, hfa_di, wr1md, bl1_md, nullptr, h_di1, hfb_di, N_DI, 256, 1);
    agg2_kernel<128><<<(N_MI + 3) / 4, 256, 0, stream>>>(h_di0, row_mi, csr_mi, agghf, N_MI);
    hgemm_f<4, true, 2><<<dim3(MI_P / 128, 4), 256, 0, stream>>>(
        agghf, wl1dm, hfa_mi, wr1dm, bl1_dm, nullptr, h_mi1, hfb_mi, N_MI, 256, 1);

    // ---- Layer 2: 256 -> 128, relu ----
    agg2_kernel<256><<<(N_DI + 3) / 4, 256, 0, stream>>>(h_mi1, row_di, csr_di, agghf, N_DI);
    hgemm_f<8, true, 1><<<dim3(DI_P / 64, 2), 256, 0, stream>>>(
        agghf, wl2md, hfb_di, wr2md, bl2_md, nullptr, h_di0, hfa_di, N_DI, 128, 1);
    agg2_kernel<256><<<(N_MI + 3) / 4, 256, 0, stream>>>(h_di1, row_mi, csr_mi, agghf, N_MI);
    hgemm_f<8, true, 2><<<dim3(MI_P / 128, 2), 256, 0, stream>>>(
        agghf, wl2dm, hfb_mi, wr2dm, bl2_dm, nullptr, h_mi0, hfa_mi, N_MI, 128, 1);

    // ---- Layer 3: 128 -> 64, no relu (no frag out needed) ----
    agg2_kernel<128><<<(N_DI + 3) / 4, 256, 0, stream>>>(h_mi0, row_di, csr_di, agghf, N_DI);
    hgemm_f<4, true, 1><<<dim3(DI_P / 64, 1), 256, 0, stream>>>(
        agghf, wl3md, hfa_di, wr3md, bl3_md, nullptr, h_di1, nullptr, N_DI, 64, 0);
    agg2_kernel<128><<<(N_MI + 3) / 4, 256, 0, stream>>>(
        h_di0, row_mi, csr_mi, agghf, N_MI);
    hgemm_f<4, true, 1><<<dim3(MI_P / 64, 1), 256, 0, stream>>>(
        agghf, wl3dm, hfa_mi, wr3dm, bl3_dm, nullptr, h_mi1, nullptr, N_MI, 64, 0);

    // ---- classifier ----
    classify_kernel<<<((long)L * 16 + 255) / 256, 256, 0, stream>>>(
        h_mi1, h_di1, label_src, label_dst, out, L);
}

// Round 4
// 776.683 us; speedup vs baseline: 1.2482x; 1.0651x over previous
//
#include <hip/hip_runtime.h>

#define N_MI 100000
#define N_DI 50000
#define MI_P 100352   // multiple of 256
#define DI_P 50176    // multiple of 256

#define SCAN_CHUNK 2048
#define NB_DI ((N_DI + SCAN_CHUNK - 1) / SCAN_CHUNK)   // 25
#define NB_MI ((N_MI + SCAN_CHUNK - 1) / SCAN_CHUNK)   // 49

typedef _Float16 half8  __attribute__((ext_vector_type(8)));
typedef _Float16 half4  __attribute__((ext_vector_type(4)));
typedef float    floatx4 __attribute__((ext_vector_type(4)));

// ---------------------------------------------------------------------------
// Hierarchical scan (CSR row offsets)
// ---------------------------------------------------------------------------
__global__ __launch_bounds__(256) void scan_part_kernel(const int* __restrict__ deg_di,
                                                        const int* __restrict__ deg_mi,
                                                        int* __restrict__ row_di,
                                                        int* __restrict__ row_mi,
                                                        int* __restrict__ bsum) {
    const int* deg; int* row; int n; int* bs;
    if (blockIdx.y == 0) { deg = deg_di; row = row_di; n = N_DI; bs = bsum; }
    else                 { deg = deg_mi; row = row_mi; n = N_MI; bs = bsum + 64; }
    int nb = (n + SCAN_CHUNK - 1) / SCAN_CHUNK;
    if ((int)blockIdx.x >= nb) return;
    int t = threadIdx.x;
    int base = blockIdx.x * SCAN_CHUNK + t * 8;
    int v[8]; int s = 0;
    #pragma unroll
    for (int e = 0; e < 8; ++e) {
        int i = base + e;
        v[e] = (i < n) ? deg[i] : 0;
        s += v[e];
    }
    int lane = t & 63, w = t >> 6;
    int x = s;
    #pragma unroll
    for (int off = 1; off < 64; off <<= 1) {
        int y = __shfl_up(x, off, 64);
        if (lane >= off) x += y;
    }
    __shared__ int wsum[4];
    if (lane == 63) wsum[w] = x;
    __syncthreads();
    int woff = 0;
    #pragma unroll
    for (int i = 0; i < 3; ++i) if (i < w) woff += wsum[i];
    int run = woff + x - s;
    #pragma unroll
    for (int e = 0; e < 8; ++e) {
        int i = base + e;
        if (i < n) row[i] = run;
        run += v[e];
    }
    if (t == 255) bs[blockIdx.x] = woff + x;
}

__global__ void scan_sums_kernel(int* __restrict__ bsum, int* __restrict__ row_di,
                                 int* __restrict__ row_mi) {
    int w = threadIdx.x >> 6, lane = threadIdx.x & 63;
    int nb = (w == 0) ? NB_DI : NB_MI;
    int* bs = bsum + w * 64;
    int v = (lane < nb) ? bs[lane] : 0;
    int x = v;
    #pragma unroll
    for (int off = 1; off < 64; off <<= 1) {
        int y = __shfl_up(x, off, 64);
        if (lane >= off) x += y;
    }
    if (lane < nb) bs[lane] = x - v;
    if (lane == nb - 1) {
        if (w == 0) row_di[N_DI] = x;
        else        row_mi[N_MI] = x;
    }
}

__global__ __launch_bounds__(256) void scan_add_kernel(const int* __restrict__ bsum,
                                                       int* __restrict__ row_di,
                                                       int* __restrict__ row_mi) {
    int* row; int n; const int* bs;
    if (blockIdx.y == 0) { row = row_di; n = N_DI; bs = bsum; }
    else                 { row = row_mi; n = N_MI; bs = bsum + 64; }
    int nb = (n + SCAN_CHUNK - 1) / SCAN_CHUNK;
    int b = blockIdx.x;
    if (b >= nb || b == 0) return;
    int off = bs[b];
    int base = b * SCAN_CHUNK + threadIdx.x;
    #pragma unroll
    for (int e = 0; e < 8; ++e) {
        int i = base + e * 256;
        if (i < n) row[i] += off;
    }
}

// ---------------------------------------------------------------------------
// Fragment-linear layout for an [Mpad x K] operand (K = KI*32):
//   chunk c (8 halves): lane=c&63 (lr=lane&15 -> row-in-16, q=lane>>4 -> ksub),
//   i=(c>>6)&3 (16-row group), k=(c>>8)%KI, mt=(c>>8)/KI (64-row tile).
//   element: row = mt*64+i*16+lr, col = k*32+q*8+e.
// ---------------------------------------------------------------------------

struct CvtW {
    const float* s[14];
    _Float16* d[14];
    int K[14];
    int KI[14];
    int nch[14];
};

__device__ __forceinline__ void cvtw_body(const CvtW& a, int b) {
    int arr = b / 16;
    int c = (b % 16) * 256 + threadIdx.x;
    if (c >= a.nch[arr]) return;
    int K = a.K[arr], KI = a.KI[arr];
    int lane = c & 63;
    int j = (c >> 6) & 3;
    int rest = c >> 8;
    int k = rest % KI;
    int p = rest / KI;
    int row = p * 64 + j * 16 + (lane & 15);
    int kcol = k * 32 + (lane >> 4) * 8;
    const float* s = a.s[arr] + (long)row * K + kcol;
    float4 u = *(const float4*)s;
    float4 v = *(const float4*)(s + 4);
    half8 h = {(_Float16)u.x, (_Float16)u.y, (_Float16)u.z, (_Float16)u.w,
               (_Float16)v.x, (_Float16)v.y, (_Float16)v.z, (_Float16)v.w};
    *(half8*)(a.d[arr] + (long)c * 8) = h;
}

// fp32 row-major [M x K] -> frag-linear fp16, LDS transpose.
template<int K>
__device__ __forceinline__ void cvt_frag_body(const float* __restrict__ in,
                                              _Float16* __restrict__ out, int M,
                                              int tile, _Float16* lds) {
    constexpr int KI = K / 32;
    constexpr int CPR = K / 8;
    const int tid = threadIdx.x;
    #pragma unroll
    for (int it = 0; it < KI; ++it) {
        int c = tid + it * 256;
        int r = c / CPR, col = c % CPR;
        int row = tile * 64 + r;
        if (row >= M) row = M - 1;
        const float* g = in + (long)row * K + col * 8;
        float4 u = *(const float4*)g;
        float4 v = *(const float4*)(g + 4);
        half8 h = {(_Float16)u.x, (_Float16)u.y, (_Float16)u.z, (_Float16)u.w,
                   (_Float16)v.x, (_Float16)v.y, (_Float16)v.z, (_Float16)v.w};
        *(half8*)&lds[r * (K + 8) + col * 8] = h;
    }
    __syncthreads();
    #pragma unroll
    for (int it = 0; it < KI; ++it) {
        int c = tid + it * 256;
        int lane = c & 63, i = (c >> 6) & 3, k = c >> 8;
        half8 h = *(const half8*)&lds[(i * 16 + (lane & 15)) * (K + 8) + k * 32 + (lane >> 4) * 8];
        *(half8*)(out + ((long)tile * 8 * K + c) * 8) = h;
    }
}

// ---------------------------------------------------------------------------
// prep dispatcher: count (atomics) || W convert || x->frag converts.
// All paths independent; count blocks first (latency-bound, resident early).
// ---------------------------------------------------------------------------
struct Prep {
    const int* src; const int* dst;
    int* deg_mi; int* deg_di;
    int E; int ncount;
    CvtW cw;
    const float* xmi; const float* xdi;
    _Float16* ofmi; _Float16* ofdi;
};

__global__ __launch_bounds__(256) void prep_kernel(Prep a) {
    __shared__ _Float16 lds[64 * 264];   // sized for cvt_frag<256>
    int b = blockIdx.x;
    if (b < a.ncount) {
        int i = b * 256 + threadIdx.x;
        if (i < a.E) {
            atomicAdd(&a.deg_mi[a.src[i]], 1);
            atomicAdd(&a.deg_di[a.dst[i]], 1);
        }
        return;
    }
    b -= a.ncount;
    if (b < 224) { cvtw_body(a.cw, b); return; }
    b -= 224;
    if (b < MI_P / 64) { cvt_frag_body<256>(a.xmi, a.ofmi, N_MI, b, lds); return; }
    b -= MI_P / 64;
    cvt_frag_body<128>(a.xdi, a.ofdi, N_DI, b, lds);
}

// ---------------------------------------------------------------------------
// Mean aggregation: one node per wave; reads row-major h, WRITES FRAG-LINEAR.
// ---------------------------------------------------------------------------
template<int DIN>
__global__ __launch_bounds__(256) void agg2_kernel(const _Float16* __restrict__ hsrc,
                                                   const int* __restrict__ row,
                                                   const int* __restrict__ csr,
                                                   _Float16* __restrict__ outf, int n) {
    constexpr int LPR = DIN / 8;
    constexpr int GR  = 64 / LPR;
    constexpr int KI  = DIN / 32;
    int node = blockIdx.x * 4 + (threadIdx.x >> 6);
    if (node >= n) return;
    int lane = threadIdx.x & 63;
    int g = lane / LPR, c = lane % LPR;
    int beg = row[node], end = row[node + 1];
    float acc[8] = {};
    #pragma unroll 2
    for (int j = beg + g; j < end; j += GR) {
        half8 v = *(const half8*)(hsrc + (long)csr[j] * DIN + c * 8);
        #pragma unroll
        for (int e = 0; e < 8; ++e) acc[e] += (float)v[e];
    }
    float inv = 1.f / (float)max(end - beg, 1);
    half8 o;
    #pragma unroll
    for (int e = 0; e < 8; ++e) {
        float s = acc[e];
        s += __shfl_down(s, 32);
        if (GR == 4) s += __shfl_down(s, 16);
        o[e] = (_Float16)(s * inv);
    }
    if (g == 0) {
        int mt = node >> 6, ii = (node >> 4) & 3, lrm = node & 15;
        long off = (((long)mt * KI + (c >> 2)) * 4 + ii) * 512 + (lrm + 16 * (c & 3)) * 8;
        *(half8*)(outf + off) = o;
    }
}

// ---------------------------------------------------------------------------
// Fragment-linear fp16 MFMA GEMM body (shared by standalone + fused kernels).
// Wave tile = (MR*16) x 64.  Epilogue stages fp16 tile in per-wave LDS, then
//   - vectorized row-major store (with optional vectorized fp32 Cadd+relu)
//   - optional frag-linear store to Cf (feeds the next GEMM's A operand)
// ---------------------------------------------------------------------------
template<int KI, bool DUAL, int MR, bool CADD>
__device__ __forceinline__ void hgemm_body(
    const _Float16* __restrict__ A1f, const _Float16* __restrict__ W1f,
    const _Float16* __restrict__ A2f, const _Float16* __restrict__ W2f,
    const float* __restrict__ bias, const float* __restrict__ Cadd,
    _Float16* __restrict__ C, _Float16* __restrict__ Cf,
    int M, int N, int relu, int bx, int p, _Float16* lds)
{
    const int wave = threadIdx.x >> 6, lane = threadIdx.x & 63;
    const int quad = lane >> 4, lr = lane & 15;
    const int g0 = (bx * 4 + wave) * MR;
    const int mt = g0 >> 2, i0 = g0 & 3;
    const long abase = ((long)(mt * KI * 4 + i0)) * 512 + lane * 8;
    const long wbase = ((long)p * KI * 4) * 512 + lane * 8;
    _Float16* lw = lds + wave * (MR * 16 * 72);

    floatx4 acc[MR][4] = {};

    #pragma unroll
    for (int pass = 0; pass < (DUAL ? 2 : 1); ++pass) {
        const _Float16* A = pass ? A2f : A1f;
        const _Float16* W = pass ? W2f : W1f;
        #pragma unroll
        for (int k = 0; k < KI; ++k) {
            half8 af[MR], bf[4];
            #pragma unroll
            for (int i = 0; i < MR; ++i)
                af[i] = *(const half8*)(A + abase + (k * 4 + i) * 512);
            #pragma unroll
            for (int j = 0; j < 4; ++j)
                bf[j] = *(const half8*)(W + wbase + (k * 4 + j) * 512);
            #pragma unroll
            for (int i = 0; i < MR; ++i)
                #pragma unroll
                for (int j = 0; j < 4; ++j)
                    acc[i][j] = __builtin_amdgcn_mfma_f32_16x16x32_f16(af[i], bf[j], acc[i][j], 0, 0, 0);
        }
    }

    // ---- stage fp16 tile in LDS (C/D layout: col=lr, row=quad*4+r)
    const int m0 = g0 * 16, n0 = p * 64;
    #pragma unroll
    for (int ii = 0; ii < MR; ++ii) {
        #pragma unroll
        for (int j = 0; j < 4; ++j) {
            float bn = bias[n0 + j * 16 + lr];
            #pragma unroll
            for (int r = 0; r < 4; ++r) {
                float v = acc[ii][j][r] + bn;
                if (!CADD && relu) v = fmaxf(v, 0.f);
                lw[(ii * 16 + quad * 4 + r) * 72 + j * 16 + lr] = (_Float16)v;
            }
        }
    }
    __syncthreads();

    // ---- row-major store: 8 lanes x half8 cover one 64-col row; 8 rows/pass.
    //      CADD: coalesced float4 pair per lane, add+relu, write back for Cf.
    const int r2 = lane >> 3, cs = lane & 7;
    #pragma unroll
    for (int ii = 0; ii < MR * 2; ++ii) {
        int m = m0 + ii * 8 + r2;
        half8 h = *(const half8*)&lw[(ii * 8 + r2) * 72 + cs * 8];
        if (CADD) {
            if (m < M) {
                const float* g = Cadd + (long)m * N + n0 + cs * 8;
                float4 u = *(const float4*)g;
                float4 v = *(const float4*)(g + 4);
                float t[8] = {u.x, u.y, u.z, u.w, v.x, v.y, v.z, v.w};
                #pragma unroll
                for (int e = 0; e < 8; ++e) {
                    float x = (float)h[e] + t[e];
                    if (relu) x = fmaxf(x, 0.f);
                    h[e] = (_Float16)x;
                }
            }
            *(half8*)&lw[(ii * 8 + r2) * 72 + cs * 8] = h;
        }
        if (m < M)
            *(half8*)(C + (long)m * N + n0 + cs * 8) = h;
    }
    if (CADD) __syncthreads();

    // ---- frag-linear store (A-operand layout for the next GEMM)
    if (Cf) {
        const int KIn = N >> 5;
        #pragma unroll
        for (int ii = 0; ii < MR; ++ii) {
            #pragma unroll
            for (int k2 = 0; k2 < 2; ++k2) {
                half8 h = *(const half8*)&lw[(ii * 16 + lr) * 72 + k2 * 32 + quad * 8];
                *(half8*)(Cf + ((long)(mt * KIn + p * 2 + k2) * 4 + i0 + ii) * 512 + lane * 8) = h;
            }
        }
    }
}

template<int KI, bool DUAL, int MR>
__global__ __launch_bounds__(256, 4) void hgemm_f(
    const _Float16* __restrict__ A1f, const _Float16* __restrict__ W1f,
    const _Float16* __restrict__ A2f, const _Float16* __restrict__ W2f,
    const float* __restrict__ bias,
    _Float16* __restrict__ C, _Float16* __restrict__ Cf, int M, int N, int relu)
{
    __shared__ _Float16 lds[4 * MR * 16 * 72];
    hgemm_body<KI, DUAL, MR, false>(A1f, W1f, A2f, W2f, bias, nullptr,
                                    C, Cf, M, N, relu, blockIdx.x, blockIdx.y, lds);
}

// ---------------------------------------------------------------------------
// fused init dispatcher: CSR fill (latency-bound, blocks first) || init GEMMs.
// fill only needs scan output; GEMMs only need prep output -> independent.
// ---------------------------------------------------------------------------
struct FusedInit {
    const int* src; const int* dst;
    const int* row_mi; const int* row_di;
    int* cur_mi; int* cur_di; int* csr_mi; int* csr_di;
    int E; int nfill;
    const _Float16* Ami; const _Float16* Wmi; const float* bmi; const float* embmi;
    _Float16* Cmi; _Float16* Cfmi;
    const _Float16* Adi; const _Float16* Wdi; const float* bdi; const float* embdi;
    _Float16* Cdi; _Float16* Cfdi;
};

__global__ __launch_bounds__(256, 4) void fused_init_kernel(FusedInit a) {
    __shared__ _Float16 lds[4 * 2 * 16 * 72];   // sized for MR=2
    int b = blockIdx.x;
    if (b < a.nfill) {
        int i = b * 256 + threadIdx.x;
        if (i < a.E) {
            int s = a.src[i], d = a.dst[i];
            int p = atomicAdd(&a.cur_di[d], 1);
            a.csr_di[a.row_di[d] + p] = s;
            int q = atomicAdd(&a.cur_mi[s], 1);
            a.csr_mi[a.row_mi[s] + q] = d;
        }
        return;
    }
    b -= a.nfill;
    if (b < (MI_P / 128) * 2) {
        hgemm_body<8, false, 2, true>(a.Ami, a.Wmi, nullptr, nullptr, a.bmi, a.embmi,
                                      a.Cmi, a.Cfmi, N_MI, 128, 0, b >> 1, b & 1, lds);
        return;
    }
    b -= (MI_P / 128) * 2;
    hgemm_body<4, false, 1, true>(a.Adi, a.Wdi, nullptr, nullptr, a.bdi, a.embdi,
                                  a.Cdi, a.Cfdi, N_DI, 128, 0, b >> 1, b & 1, lds);
}

// ---------------------------------------------------------------------------
// Classifier: out[e] = dot64(h_mi[ls[e]], h_di[ld[e]]), fp16 in, fp32 out
// ---------------------------------------------------------------------------
__global__ void classify_kernel(const _Float16* __restrict__ hmi, const _Float16* __restrict__ hdi,
                                const int* __restrict__ ls, const int* __restrict__ ld,
                                float* __restrict__ out, int L) {
    long idx = (long)blockIdx.x * blockDim.x + threadIdx.x;
    int e = (int)(idx >> 4), q = (int)(idx & 15);
    if (e >= L) return;
    const half4* ra = (const half4*)(hmi + (long)ls[e] * 64);
    const half4* rb = (const half4*)(hdi + (long)ld[e] * 64);
    half4 a = ra[q], b = rb[q];
    float s = (float)a.x * (float)b.x + (float)a.y * (float)b.y +
              (float)a.z * (float)b.z + (float)a.w * (float)b.w;
    #pragma unroll
    for (int off = 8; off >= 1; off >>= 1) s += __shfl_down(s, off, 16);
    if (q == 0) out[e] = s;
}

// ---------------------------------------------------------------------------
// Launch
// ---------------------------------------------------------------------------
extern "C" void kernel_launch(void* const* d_in, const int* in_sizes, int n_in,
                              void* d_out, int out_size, void* d_ws, size_t ws_size,
                              hipStream_t stream) {
    const float* x_mi   = (const float*)d_in[0];
    const float* x_di   = (const float*)d_in[1];
    const float* W_mi   = (const float*)d_in[2];
    const float* b_mi   = (const float*)d_in[3];
    const float* W_di   = (const float*)d_in[4];
    const float* b_di   = (const float*)d_in[5];
    const float* emb_mi = (const float*)d_in[6];
    const float* emb_di = (const float*)d_in[7];
    const float* Wl1_md = (const float*)d_in[8];
    const float* bl1_md = (const float*)d_in[9];
    const float* Wr1_md = (const float*)d_in[10];
    const float* Wl1_dm = (const float*)d_in[11];
    const float* bl1_dm = (const float*)d_in[12];
    const float* Wr1_dm = (const float*)d_in[13];
    const float* Wl2_md = (const float*)d_in[14];
    const float* bl2_md = (const float*)d_in[15];
    const float* Wr2_md = (const float*)d_in[16];
    const float* Wl2_dm = (const float*)d_in[17];
    const float* bl2_dm = (const float*)d_in[18];
    const float* Wr2_dm = (const float*)d_in[19];
    const float* Wl3_md = (const float*)d_in[20];
    const float* bl3_md = (const float*)d_in[21];
    const float* Wr3_md = (const float*)d_in[22];
    const float* Wl3_dm = (const float*)d_in[23];
    const float* bl3_dm = (const float*)d_in[24];
    const float* Wr3_dm = (const float*)d_in[25];
    const int* edge_src  = (const int*)d_in[26];
    const int* edge_dst  = (const int*)d_in[27];
    const int* label_src = (const int*)d_in[28];
    const int* label_dst = (const int*)d_in[29];
    const int E = in_sizes[26];
    const int L = in_sizes[28];
    float* out = (float*)d_out;

    // ---- workspace layout ----
    _Float16* hp = (_Float16*)d_ws;
    _Float16* wWmi  = hp; hp += 128 * 256;
    _Float16* wWdi  = hp; hp += 128 * 128;
    _Float16* wl1md = hp; hp += 256 * 128;
    _Float16* wr1md = hp; hp += 256 * 128;
    _Float16* wl1dm = hp; hp += 256 * 128;
    _Float16* wr1dm = hp; hp += 256 * 128;
    _Float16* wl2md = hp; hp += 128 * 256;
    _Float16* wr2md = hp; hp += 128 * 256;
    _Float16* wl2dm = hp; hp += 128 * 256;
    _Float16* wr2dm = hp; hp += 128 * 256;
    _Float16* wl3md = hp; hp += 64 * 128;
    _Float16* wr3md = hp; hp += 64 * 128;
    _Float16* wl3dm = hp; hp += 64 * 128;
    _Float16* wr3dm = hp; hp += 64 * 128;
    _Float16* h_mi0 = hp; hp += (long)MI_P * 128;   // row-major h (init/L2 out)
    _Float16* h_mi1 = hp; hp += (long)MI_P * 256;   // row-major h (L1/L3 out)
    _Float16* h_di0 = hp; hp += (long)DI_P * 128;
    _Float16* h_di1 = hp; hp += (long)DI_P * 256;
    _Float16* hfa_mi = hp; hp += (long)MI_P * 128;  // frag h (init/L2 out)
    _Float16* hfb_mi = hp; hp += (long)MI_P * 256;  // frag x / frag h (L1 out)
    _Float16* hfa_di = hp; hp += (long)DI_P * 128;
    _Float16* hfb_di = hp; hp += (long)DI_P * 256;
    _Float16* agghf  = hp; hp += (long)MI_P * 256;  // frag-linear agg output

    int* ip = (int*)hp;
    int* deg_di = ip;  ip += N_DI;
    int* deg_mi = ip;  ip += N_MI;
    int* cur_di = ip;  ip += N_DI;
    int* cur_mi = ip;  ip += N_MI;
    int* row_di = ip;  ip += N_DI + 1;
    int* row_mi = ip;  ip += N_MI + 1;
    int* csr_di = ip;  ip += E;
    int* csr_mi = ip;  ip += E;
    int* bsum   = ip;  ip += 128;

    int eb = (E + 255) / 256;

    // ---- zero deg + cur ----
    hipMemsetAsync(deg_di, 0, (size_t)(2 * (N_DI + N_MI)) * sizeof(int), stream);

    // ---- prep: count || W converts || x->frag converts ----
    Prep pr;
    pr.src = edge_src; pr.dst = edge_dst;
    pr.deg_mi = deg_mi; pr.deg_di = deg_di;
    pr.E = E; pr.ncount = eb;
    const float* srcs[14] = {W_mi, W_di, Wl1_md, Wr1_md, Wl1_dm, Wr1_dm,
                             Wl2_md, Wr2_md, Wl2_dm, Wr2_dm, Wl3_md, Wr3_md, Wl3_dm, Wr3_dm};
    _Float16* dsts[14] = {wWmi, wWdi, wl1md, wr1md, wl1dm, wr1dm,
                          wl2md, wr2md, wl2dm, wr2dm, wl3md, wr3md, wl3dm, wr3dm};
    int Ks[14]  = {256, 128, 128, 128, 128, 128, 256, 256, 256, 256, 128, 128, 128, 128};
    int Ns[14]  = {128, 128, 256, 256, 256, 256, 128, 128, 128, 128, 64, 64, 64, 64};
    for (int i = 0; i < 14; ++i) {
        pr.cw.s[i] = srcs[i]; pr.cw.d[i] = dsts[i];
        pr.cw.K[i] = Ks[i]; pr.cw.KI[i] = Ks[i] / 32;
        pr.cw.nch[i] = Ns[i] * Ks[i] / 8;
    }
    pr.xmi = x_mi; pr.xdi = x_di; pr.ofmi = hfb_mi; pr.ofdi = hfb_di;
    int prep_blocks = eb + 224 + MI_P / 64 + DI_P / 64;
    prep_kernel<<<prep_blocks, 256, 0, stream>>>(pr);

    // ---- scan (needs count) ----
    scan_part_kernel<<<dim3(NB_MI, 2), 256, 0, stream>>>(deg_di, deg_mi, row_di, row_mi, bsum);
    scan_sums_kernel<<<1, 128, 0, stream>>>(bsum, row_di, row_mi);
    scan_add_kernel<<<dim3(NB_MI, 2), 256, 0, stream>>>(bsum, row_di, row_mi);

    // ---- fused: fill || init GEMMs (h0 = x @ W^T + b + emb) ----
    FusedInit fi;
    fi.src = edge_src; fi.dst = edge_dst;
    fi.row_mi = row_mi; fi.row_di = row_di;
    fi.cur_mi = cur_mi; fi.cur_di = cur_di;
    fi.csr_mi = csr_mi; fi.csr_di = csr_di;
    fi.E = E; fi.nfill = eb;
    fi.Ami = hfb_mi; fi.Wmi = wWmi; fi.bmi = b_mi; fi.embmi = emb_mi;
    fi.Cmi = h_mi0; fi.Cfmi = hfa_mi;
    fi.Adi = hfb_di; fi.Wdi = wWdi; fi.bdi = b_di; fi.embdi = emb_di;
    fi.Cdi = h_di0; fi.Cfdi = hfa_di;
    int fused_blocks = eb + (MI_P / 128) * 2 + (DI_P / 64) * 2;
    fused_init_kernel<<<fused_blocks, 256, 0, stream>>>(fi);

    // ---- Layer 1: 128 -> 256, relu ----
    agg2_kernel<128><<<(N_DI + 3) / 4, 256, 0, stream>>>(h_mi0, row_di, csr_di, agghf, N_DI);
    hgemm_f<4, true, 1><<<dim3(DI_P / 64, 4), 256, 0, stream>>>(
        agghf, wl1md, hfa_di, wr1md, bl1_md, h_di1, hfb_di, N_DI, 256, 1);
    agg2_kernel<128><<<(N_MI + 3) / 4, 256, 0, stream>>>(h_di0, row_mi, csr_mi, agghf, N_MI);
    hgemm_f<4, true, 2><<<dim3(MI_P / 128, 4), 256, 0, stream>>>(
        agghf, wl1dm, hfa_mi, wr1dm, bl1_dm, h_mi1, hfb_mi, N_MI, 256, 1);

    // ---- Layer 2: 256 -> 128, relu ----
    agg2_kernel<256><<<(N_DI + 3) / 4, 256, 0, stream>>>(h_mi1, row_di, csr_di, agghf, N_DI);
    hgemm_f<8, true, 1><<<dim3(DI_P / 64, 2), 256, 0, stream>>>(
        agghf, wl2md, hfb_di, wr2md, bl2_md, h_di0, hfa_di, N_DI, 128, 1);
    agg2_kernel<256><<<(N_MI + 3) / 4, 256, 0, stream>>>(h_di1, row_mi, csr_mi, agghf, N_MI);
    hgemm_f<8, true, 2><<<dim3(MI_P / 128, 2), 256, 0, stream>>>(
        agghf, wl2dm, hfb_mi, wr2dm, bl2_dm, h_mi0, hfa_mi, N_MI, 128, 1);

    // ---- Layer 3: 128 -> 64, no relu ----
    agg2_kernel<128><<<(N_DI + 3) / 4, 256, 0, stream>>>(h_mi0, row_di, csr_di, agghf, N_DI);
    hgemm_f<4, true, 1><<<dim3(DI_P / 64, 1), 256, 0, stream>>>(
        agghf, wl3md, hfa_di, wr3md, bl3_md, h_di1, nullptr, N_DI, 64, 0);
    agg2_kernel<128><<<(N_MI + 3) / 4, 256, 0, stream>>>(h_di0, row_mi, csr_mi, agghf, N_MI);
    hgemm_f<4, true, 1><<<dim3(MI_P / 64, 1), 256, 0, stream>>>(
        agghf, wl3dm, hfa_mi, wr3dm, bl3_dm, h_mi1, nullptr, N_MI, 64, 0);

    // ---- classifier ----
    classify_kernel<<<((long)L * 16 + 255) / 256, 256, 0, stream>>>(
        h_mi1, h_di1, label_src, label_dst, out, L);
}

// Round 5
// 766.951 us; speedup vs baseline: 1.2641x; 1.0127x over previous
//
#include <hip/hip_runtime.h>

#define N_MI 100000
#define N_DI 50000
#define MI_P 100352   // multiple of 256
#define DI_P 50176    // multiple of 256

#define SCAN_CHUNK 2048
#define NB_DI ((N_DI + SCAN_CHUNK - 1) / SCAN_CHUNK)   // 25
#define NB_MI ((N_MI + SCAN_CHUNK - 1) / SCAN_CHUNK)   // 49

typedef _Float16 half8  __attribute__((ext_vector_type(8)));
typedef _Float16 half4  __attribute__((ext_vector_type(4)));
typedef float    floatx4 __attribute__((ext_vector_type(4)));

// ---------------------------------------------------------------------------
// Hierarchical scan (CSR row offsets)
// ---------------------------------------------------------------------------
__global__ __launch_bounds__(256) void scan_part_kernel(const int* __restrict__ deg_di,
                                                        const int* __restrict__ deg_mi,
                                                        int* __restrict__ row_di,
                                                        int* __restrict__ row_mi,
                                                        int* __restrict__ bsum) {
    const int* deg; int* row; int n; int* bs;
    if (blockIdx.y == 0) { deg = deg_di; row = row_di; n = N_DI; bs = bsum; }
    else                 { deg = deg_mi; row = row_mi; n = N_MI; bs = bsum + 64; }
    int nb = (n + SCAN_CHUNK - 1) / SCAN_CHUNK;
    if ((int)blockIdx.x >= nb) return;
    int t = threadIdx.x;
    int base = blockIdx.x * SCAN_CHUNK + t * 8;
    int v[8]; int s = 0;
    #pragma unroll
    for (int e = 0; e < 8; ++e) {
        int i = base + e;
        v[e] = (i < n) ? deg[i] : 0;
        s += v[e];
    }
    int lane = t & 63, w = t >> 6;
    int x = s;
    #pragma unroll
    for (int off = 1; off < 64; off <<= 1) {
        int y = __shfl_up(x, off, 64);
        if (lane >= off) x += y;
    }
    __shared__ int wsum[4];
    if (lane == 63) wsum[w] = x;
    __syncthreads();
    int woff = 0;
    #pragma unroll
    for (int i = 0; i < 3; ++i) if (i < w) woff += wsum[i];
    int run = woff + x - s;
    #pragma unroll
    for (int e = 0; e < 8; ++e) {
        int i = base + e;
        if (i < n) row[i] = run;
        run += v[e];
    }
    if (t == 255) bs[blockIdx.x] = woff + x;
}

__global__ void scan_sums_kernel(int* __restrict__ bsum, int* __restrict__ row_di,
                                 int* __restrict__ row_mi) {
    int w = threadIdx.x >> 6, lane = threadIdx.x & 63;
    int nb = (w == 0) ? NB_DI : NB_MI;
    int* bs = bsum + w * 64;
    int v = (lane < nb) ? bs[lane] : 0;
    int x = v;
    #pragma unroll
    for (int off = 1; off < 64; off <<= 1) {
        int y = __shfl_up(x, off, 64);
        if (lane >= off) x += y;
    }
    if (lane < nb) bs[lane] = x - v;
    if (lane == nb - 1) {
        if (w == 0) row_di[N_DI] = x;
        else        row_mi[N_MI] = x;
    }
}

__global__ __launch_bounds__(256) void scan_add_kernel(const int* __restrict__ bsum,
                                                       int* __restrict__ row_di,
                                                       int* __restrict__ row_mi) {
    int* row; int n; const int* bs;
    if (blockIdx.y == 0) { row = row_di; n = N_DI; bs = bsum; }
    else                 { row = row_mi; n = N_MI; bs = bsum + 64; }
    int nb = (n + SCAN_CHUNK - 1) / SCAN_CHUNK;
    int b = blockIdx.x;
    if (b >= nb || b == 0) return;
    int off = bs[b];
    int base = b * SCAN_CHUNK + threadIdx.x;
    #pragma unroll
    for (int e = 0; e < 8; ++e) {
        int i = base + e * 256;
        if (i < n) row[i] += off;
    }
}

// ---------------------------------------------------------------------------
// Fragment-linear layout for an [Mpad x K] operand (K = KI*32):
//   chunk c (8 halves): lane=c&63 (lr=lane&15 -> row-in-16, q=lane>>4 -> ksub),
//   i=(c>>6)&3 (16-row group), k=(c>>8)%KI, mt=(c>>8)/KI (64-row tile).
//   element: row = mt*64+i*16+lr, col = k*32+q*8+e.
// ---------------------------------------------------------------------------

struct CvtW {
    const float* s[14];
    _Float16* d[14];
    int K[14];
    int KI[14];
    int nch[14];
};

__device__ __forceinline__ void cvtw_body(const CvtW& a, int b) {
    int arr = b / 16;
    int c = (b % 16) * 256 + threadIdx.x;
    if (c >= a.nch[arr]) return;
    int K = a.K[arr], KI = a.KI[arr];
    int lane = c & 63;
    int j = (c >> 6) & 3;
    int rest = c >> 8;
    int k = rest % KI;
    int p = rest / KI;
    int row = p * 64 + j * 16 + (lane & 15);
    int kcol = k * 32 + (lane >> 4) * 8;
    const float* s = a.s[arr] + (long)row * K + kcol;
    float4 u = *(const float4*)s;
    float4 v = *(const float4*)(s + 4);
    half8 h = {(_Float16)u.x, (_Float16)u.y, (_Float16)u.z, (_Float16)u.w,
               (_Float16)v.x, (_Float16)v.y, (_Float16)v.z, (_Float16)v.w};
    *(half8*)(a.d[arr] + (long)c * 8) = h;
}

// fp32 row-major [M x K] -> frag-linear fp16, LDS transpose.
template<int K>
__device__ __forceinline__ void cvt_frag_body(const float* __restrict__ in,
                                              _Float16* __restrict__ out, int M,
                                              int tile, _Float16* lds) {
    constexpr int KI = K / 32;
    constexpr int CPR = K / 8;
    const int tid = threadIdx.x;
    #pragma unroll
    for (int it = 0; it < KI; ++it) {
        int c = tid + it * 256;
        int r = c / CPR, col = c % CPR;
        int row = tile * 64 + r;
        if (row >= M) row = M - 1;
        const float* g = in + (long)row * K + col * 8;
        float4 u = *(const float4*)g;
        float4 v = *(const float4*)(g + 4);
        half8 h = {(_Float16)u.x, (_Float16)u.y, (_Float16)u.z, (_Float16)u.w,
                   (_Float16)v.x, (_Float16)v.y, (_Float16)v.z, (_Float16)v.w};
        *(half8*)&lds[r * (K + 8) + col * 8] = h;
    }
    __syncthreads();
    #pragma unroll
    for (int it = 0; it < KI; ++it) {
        int c = tid + it * 256;
        int lane = c & 63, i = (c >> 6) & 3, k = c >> 8;
        half8 h = *(const half8*)&lds[(i * 16 + (lane & 15)) * (K + 8) + k * 32 + (lane >> 4) * 8];
        *(half8*)(out + ((long)tile * 8 * K + c) * 8) = h;
    }
}

// ---------------------------------------------------------------------------
// prep dispatcher: count (atomics) || W convert || x->frag converts.
// ---------------------------------------------------------------------------
struct Prep {
    const int* src; const int* dst;
    int* deg_mi; int* deg_di;
    int E; int ncount;
    CvtW cw;
    const float* xmi; const float* xdi;
    _Float16* ofmi; _Float16* ofdi;
};

__global__ __launch_bounds__(256) void prep_kernel(Prep a) {
    __shared__ _Float16 lds[64 * 264];   // sized for cvt_frag<256>
    int b = blockIdx.x;
    if (b < a.ncount) {
        int i = b * 256 + threadIdx.x;
        if (i < a.E) {
            atomicAdd(&a.deg_mi[a.src[i]], 1);
            atomicAdd(&a.deg_di[a.dst[i]], 1);
        }
        return;
    }
    b -= a.ncount;
    if (b < 224) { cvtw_body(a.cw, b); return; }
    b -= 224;
    if (b < MI_P / 64) { cvt_frag_body<256>(a.xmi, a.ofmi, N_MI, b, lds); return; }
    b -= MI_P / 64;
    cvt_frag_body<128>(a.xdi, a.ofdi, N_DI, b, lds);
}

// ---------------------------------------------------------------------------
// Mean aggregation body: one node per wave; row-major gather, frag-linear out.
// ---------------------------------------------------------------------------
template<int DIN>
__device__ __forceinline__ void agg2_body(const _Float16* __restrict__ hsrc,
                                          const int* __restrict__ row,
                                          const int* __restrict__ csr,
                                          _Float16* __restrict__ outf, int n, int blk) {
    constexpr int LPR = DIN / 8;
    constexpr int GR  = 64 / LPR;
    constexpr int KI  = DIN / 32;
    int node = blk * 4 + (threadIdx.x >> 6);
    if (node >= n) return;
    int lane = threadIdx.x & 63;
    int g = lane / LPR, c = lane % LPR;
    int beg = row[node], end = row[node + 1];
    float acc[8] = {};
    #pragma unroll 2
    for (int j = beg + g; j < end; j += GR) {
        half8 v = *(const half8*)(hsrc + (long)csr[j] * DIN + c * 8);
        #pragma unroll
        for (int e = 0; e < 8; ++e) acc[e] += (float)v[e];
    }
    float inv = 1.f / (float)max(end - beg, 1);
    half8 o;
    #pragma unroll
    for (int e = 0; e < 8; ++e) {
        float s = acc[e];
        s += __shfl_down(s, 32);
        if (GR == 4) s += __shfl_down(s, 16);
        o[e] = (_Float16)(s * inv);
    }
    if (g == 0) {
        int mt = node >> 6, ii = (node >> 4) & 3, lrm = node & 15;
        long off = (((long)mt * KI + (c >> 2)) * 4 + ii) * 512 + (lrm + 16 * (c & 3)) * 8;
        *(half8*)(outf + off) = o;
    }
}

// fused per-layer agg: mi-agg blocks first (larger), then di-agg blocks.
struct FusedAgg {
    const _Float16* hmi; const _Float16* hdi;
    const int* row_di; const int* csr_di;
    const int* row_mi; const int* csr_mi;
    _Float16* outdi; _Float16* outmi;
    int nmib;   // mi block count
};

template<int DIN>
__global__ __launch_bounds__(256) void fused_agg_kernel(FusedAgg a) {
    int b = blockIdx.x;
    if (b < a.nmib) agg2_body<DIN>(a.hdi, a.row_mi, a.csr_mi, a.outmi, N_MI, b);
    else            agg2_body<DIN>(a.hmi, a.row_di, a.csr_di, a.outdi, N_DI, b - a.nmib);
}

// ---------------------------------------------------------------------------
// Fragment-linear fp16 MFMA GEMM body.
// Wave tile = (MR*16) x 64.  Epilogue stages fp16 tile in per-wave LDS, then
//   - vectorized row-major store (with optional vectorized fp32 Cadd+relu)
//   - optional frag-linear store to Cf (feeds the next GEMM's A operand)
// ---------------------------------------------------------------------------
template<int KI, bool DUAL, int MR, bool CADD>
__device__ __forceinline__ void hgemm_body(
    const _Float16* __restrict__ A1f, const _Float16* __restrict__ W1f,
    const _Float16* __restrict__ A2f, const _Float16* __restrict__ W2f,
    const float* __restrict__ bias, const float* __restrict__ Cadd,
    _Float16* __restrict__ C, _Float16* __restrict__ Cf,
    int M, int N, int relu, int bx, int p, _Float16* lds)
{
    const int wave = threadIdx.x >> 6, lane = threadIdx.x & 63;
    const int quad = lane >> 4, lr = lane & 15;
    const int g0 = (bx * 4 + wave) * MR;
    const int mt = g0 >> 2, i0 = g0 & 3;
    const long abase = ((long)(mt * KI * 4 + i0)) * 512 + lane * 8;
    const long wbase = ((long)p * KI * 4) * 512 + lane * 8;
    _Float16* lw = lds + wave * (MR * 16 * 72);

    floatx4 acc[MR][4] = {};

    #pragma unroll
    for (int pass = 0; pass < (DUAL ? 2 : 1); ++pass) {
        const _Float16* A = pass ? A2f : A1f;
        const _Float16* W = pass ? W2f : W1f;
        #pragma unroll
        for (int k = 0; k < KI; ++k) {
            half8 af[MR], bf[4];
            #pragma unroll
            for (int i = 0; i < MR; ++i)
                af[i] = *(const half8*)(A + abase + (k * 4 + i) * 512);
            #pragma unroll
            for (int j = 0; j < 4; ++j)
                bf[j] = *(const half8*)(W + wbase + (k * 4 + j) * 512);
            #pragma unroll
            for (int i = 0; i < MR; ++i)
                #pragma unroll
                for (int j = 0; j < 4; ++j)
                    acc[i][j] = __builtin_amdgcn_mfma_f32_16x16x32_f16(af[i], bf[j], acc[i][j], 0, 0, 0);
        }
    }

    // ---- stage fp16 tile in LDS (C/D layout: col=lr, row=quad*4+r)
    const int m0 = g0 * 16, n0 = p * 64;
    #pragma unroll
    for (int ii = 0; ii < MR; ++ii) {
        #pragma unroll
        for (int j = 0; j < 4; ++j) {
            float bn = bias[n0 + j * 16 + lr];
            #pragma unroll
            for (int r = 0; r < 4; ++r) {
                float v = acc[ii][j][r] + bn;
                if (!CADD && relu) v = fmaxf(v, 0.f);
                lw[(ii * 16 + quad * 4 + r) * 72 + j * 16 + lr] = (_Float16)v;
            }
        }
    }
    __syncthreads();

    // ---- row-major store: 8 lanes x half8 cover one 64-col row; 8 rows/pass.
    const int r2 = lane >> 3, cs = lane & 7;
    #pragma unroll
    for (int ii = 0; ii < MR * 2; ++ii) {
        int m = m0 + ii * 8 + r2;
        half8 h = *(const half8*)&lw[(ii * 8 + r2) * 72 + cs * 8];
        if (CADD) {
            if (m < M) {
                const float* g = Cadd + (long)m * N + n0 + cs * 8;
                float4 u = *(const float4*)g;
                float4 v = *(const float4*)(g + 4);
                float t[8] = {u.x, u.y, u.z, u.w, v.x, v.y, v.z, v.w};
                #pragma unroll
                for (int e = 0; e < 8; ++e) {
                    float x = (float)h[e] + t[e];
                    if (relu) x = fmaxf(x, 0.f);
                    h[e] = (_Float16)x;
                }
            }
            *(half8*)&lw[(ii * 8 + r2) * 72 + cs * 8] = h;
        }
        if (m < M)
            *(half8*)(C + (long)m * N + n0 + cs * 8) = h;
    }
    if (CADD) __syncthreads();

    // ---- frag-linear store (A-operand layout for the next GEMM)
    if (Cf) {
        const int KIn = N >> 5;
        #pragma unroll
        for (int ii = 0; ii < MR; ++ii) {
            #pragma unroll
            for (int k2 = 0; k2 < 2; ++k2) {
                half8 h = *(const half8*)&lw[(ii * 16 + lr) * 72 + k2 * 32 + quad * 8];
                *(half8*)(Cf + ((long)(mt * KIn + p * 2 + k2) * 4 + i0 + ii) * 512 + lane * 8) = h;
            }
        }
    }
}

// fused per-layer dual GEMM: mi blocks first (larger), then di blocks.
struct FusedGemm {
    const _Float16 *Ami, *Wlmi, *Rmi, *Wrmi; const float* bmi;
    _Float16 *Cmi, *Cfmi;
    const _Float16 *Adi, *Wldi, *Rdi, *Wrdi; const float* bdi;
    _Float16 *Cdi, *Cfdi;
    int nmib, xmi, xdi, Nmi, Ndi, relu;
};

template<int KI, int MRM, int MRD>
__global__ __launch_bounds__(256, 4) void fused_gemm_kernel(FusedGemm a) {
    constexpr int MRX = (MRM > MRD) ? MRM : MRD;
    __shared__ _Float16 lds[4 * MRX * 16 * 72];
    int b = blockIdx.x;
    if (b < a.nmib) {
        hgemm_body<KI, true, MRM, false>(a.Ami, a.Wlmi, a.Rmi, a.Wrmi, a.bmi, nullptr,
                                         a.Cmi, a.Cfmi, N_MI, a.Nmi, a.relu,
                                         b % a.xmi, b / a.xmi, lds);
    } else {
        b -= a.nmib;
        hgemm_body<KI, true, MRD, false>(a.Adi, a.Wldi, a.Rdi, a.Wrdi, a.bdi, nullptr,
                                         a.Cdi, a.Cfdi, N_DI, a.Ndi, a.relu,
                                         b % a.xdi, b / a.xdi, lds);
    }
}

// ---------------------------------------------------------------------------
// fused init dispatcher: CSR fill (latency-bound, blocks first) || init GEMMs.
// ---------------------------------------------------------------------------
struct FusedInit {
    const int* src; const int* dst;
    const int* row_mi; const int* row_di;
    int* cur_mi; int* cur_di; int* csr_mi; int* csr_di;
    int E; int nfill;
    const _Float16* Ami; const _Float16* Wmi; const float* bmi; const float* embmi;
    _Float16* Cmi; _Float16* Cfmi;
    const _Float16* Adi; const _Float16* Wdi; const float* bdi; const float* embdi;
    _Float16* Cdi; _Float16* Cfdi;
};

__global__ __launch_bounds__(256, 4) void fused_init_kernel(FusedInit a) {
    __shared__ _Float16 lds[4 * 2 * 16 * 72];   // sized for MR=2
    int b = blockIdx.x;
    if (b < a.nfill) {
        int i = b * 256 + threadIdx.x;
        if (i < a.E) {
            int s = a.src[i], d = a.dst[i];
            int p = atomicAdd(&a.cur_di[d], 1);
            a.csr_di[a.row_di[d] + p] = s;
            int q = atomicAdd(&a.cur_mi[s], 1);
            a.csr_mi[a.row_mi[s] + q] = d;
        }
        return;
    }
    b -= a.nfill;
    if (b < (MI_P / 128) * 2) {
        hgemm_body<8, false, 2, true>(a.Ami, a.Wmi, nullptr, nullptr, a.bmi, a.embmi,
                                      a.Cmi, a.Cfmi, N_MI, 128, 0, b >> 1, b & 1, lds);
        return;
    }
    b -= (MI_P / 128) * 2;
    hgemm_body<4, false, 1, true>(a.Adi, a.Wdi, nullptr, nullptr, a.bdi, a.embdi,
                                  a.Cdi, a.Cfdi, N_DI, 128, 0, b >> 1, b & 1, lds);
}

// ---------------------------------------------------------------------------
// Classifier: out[e] = dot64(h_mi[ls[e]], h_di[ld[e]]), fp16 in, fp32 out
// ---------------------------------------------------------------------------
__global__ void classify_kernel(const _Float16* __restrict__ hmi, const _Float16* __restrict__ hdi,
                                const int* __restrict__ ls, const int* __restrict__ ld,
                                float* __restrict__ out, int L) {
    long idx = (long)blockIdx.x * blockDim.x + threadIdx.x;
    int e = (int)(idx >> 4), q = (int)(idx & 15);
    if (e >= L) return;
    const half4* ra = (const half4*)(hmi + (long)ls[e] * 64);
    const half4* rb = (const half4*)(hdi + (long)ld[e] * 64);
    half4 a = ra[q], b = rb[q];
    float s = (float)a.x * (float)b.x + (float)a.y * (float)b.y +
              (float)a.z * (float)b.z + (float)a.w * (float)b.w;
    #pragma unroll
    for (int off = 8; off >= 1; off >>= 1) s += __shfl_down(s, off, 16);
    if (q == 0) out[e] = s;
}

// ---------------------------------------------------------------------------
// Launch
// ---------------------------------------------------------------------------
extern "C" void kernel_launch(void* const* d_in, const int* in_sizes, int n_in,
                              void* d_out, int out_size, void* d_ws, size_t ws_size,
                              hipStream_t stream) {
    const float* x_mi   = (const float*)d_in[0];
    const float* x_di   = (const float*)d_in[1];
    const float* W_mi   = (const float*)d_in[2];
    const float* b_mi   = (const float*)d_in[3];
    const float* W_di   = (const float*)d_in[4];
    const float* b_di   = (const float*)d_in[5];
    const float* emb_mi = (const float*)d_in[6];
    const float* emb_di = (const float*)d_in[7];
    const float* Wl1_md = (const float*)d_in[8];
    const float* bl1_md = (const float*)d_in[9];
    const float* Wr1_md = (const float*)d_in[10];
    const float* Wl1_dm = (const float*)d_in[11];
    const float* bl1_dm = (const float*)d_in[12];
    const float* Wr1_dm = (const float*)d_in[13];
    const float* Wl2_md = (const float*)d_in[14];
    const float* bl2_md = (const float*)d_in[15];
    const float* Wr2_md = (const float*)d_in[16];
    const float* Wl2_dm = (const float*)d_in[17];
    const float* bl2_dm = (const float*)d_in[18];
    const float* Wr2_dm = (const float*)d_in[19];
    const float* Wl3_md = (const float*)d_in[20];
    const float* bl3_md = (const float*)d_in[21];
    const float* Wr3_md = (const float*)d_in[22];
    const float* Wl3_dm = (const float*)d_in[23];
    const float* bl3_dm = (const float*)d_in[24];
    const float* Wr3_dm = (const float*)d_in[25];
    const int* edge_src  = (const int*)d_in[26];
    const int* edge_dst  = (const int*)d_in[27];
    const int* label_src = (const int*)d_in[28];
    const int* label_dst = (const int*)d_in[29];
    const int E = in_sizes[26];
    const int L = in_sizes[28];
    float* out = (float*)d_out;

    // ---- workspace layout ----
    _Float16* hp = (_Float16*)d_ws;
    _Float16* wWmi  = hp; hp += 128 * 256;
    _Float16* wWdi  = hp; hp += 128 * 128;
    _Float16* wl1md = hp; hp += 256 * 128;
    _Float16* wr1md = hp; hp += 256 * 128;
    _Float16* wl1dm = hp; hp += 256 * 128;
    _Float16* wr1dm = hp; hp += 256 * 128;
    _Float16* wl2md = hp; hp += 128 * 256;
    _Float16* wr2md = hp; hp += 128 * 256;
    _Float16* wl2dm = hp; hp += 128 * 256;
    _Float16* wr2dm = hp; hp += 128 * 256;
    _Float16* wl3md = hp; hp += 64 * 128;
    _Float16* wr3md = hp; hp += 64 * 128;
    _Float16* wl3dm = hp; hp += 64 * 128;
    _Float16* wr3dm = hp; hp += 64 * 128;
    _Float16* h_mi0 = hp; hp += (long)MI_P * 128;   // row-major h (init/L2 out)
    _Float16* h_mi1 = hp; hp += (long)MI_P * 256;   // row-major h (L1/L3 out)
    _Float16* h_di0 = hp; hp += (long)DI_P * 128;
    _Float16* h_di1 = hp; hp += (long)DI_P * 256;
    _Float16* hfa_mi = hp; hp += (long)MI_P * 128;  // frag h (init/L2 out)
    _Float16* hfb_mi = hp; hp += (long)MI_P * 256;  // frag x / frag h (L1 out)
    _Float16* hfa_di = hp; hp += (long)DI_P * 128;
    _Float16* hfb_di = hp; hp += (long)DI_P * 256;
    _Float16* aggmi  = hp; hp += (long)MI_P * 256;  // frag-linear agg (mi nodes)
    _Float16* aggdi  = hp; hp += (long)DI_P * 256;  // frag-linear agg (di nodes)

    int* ip = (int*)hp;
    int* deg_di = ip;  ip += N_DI;
    int* deg_mi = ip;  ip += N_MI;
    int* cur_di = ip;  ip += N_DI;
    int* cur_mi = ip;  ip += N_MI;
    int* row_di = ip;  ip += N_DI + 1;
    int* row_mi = ip;  ip += N_MI + 1;
    int* csr_di = ip;  ip += E;
    int* csr_mi = ip;  ip += E;
    int* bsum   = ip;  ip += 128;

    int eb = (E + 255) / 256;

    // ---- zero deg + cur ----
    hipMemsetAsync(deg_di, 0, (size_t)(2 * (N_DI + N_MI)) * sizeof(int), stream);

    // ---- prep: count || W converts || x->frag converts ----
    Prep pr;
    pr.src = edge_src; pr.dst = edge_dst;
    pr.deg_mi = deg_mi; pr.deg_di = deg_di;
    pr.E = E; pr.ncount = eb;
    const float* srcs[14] = {W_mi, W_di, Wl1_md, Wr1_md, Wl1_dm, Wr1_dm,
                             Wl2_md, Wr2_md, Wl2_dm, Wr2_dm, Wl3_md, Wr3_md, Wl3_dm, Wr3_dm};
    _Float16* dsts[14] = {wWmi, wWdi, wl1md, wr1md, wl1dm, wr1dm,
                          wl2md, wr2md, wl2dm, wr2dm, wl3md, wr3md, wl3dm, wr3dm};
    int Ks[14]  = {256, 128, 128, 128, 128, 128, 256, 256, 256, 256, 128, 128, 128, 128};
    int Ns[14]  = {128, 128, 256, 256, 256, 256, 128, 128, 128, 128, 64, 64, 64, 64};
    for (int i = 0; i < 14; ++i) {
        pr.cw.s[i] = srcs[i]; pr.cw.d[i] = dsts[i];
        pr.cw.K[i] = Ks[i]; pr.cw.KI[i] = Ks[i] / 32;
        pr.cw.nch[i] = Ns[i] * Ks[i] / 8;
    }
    pr.xmi = x_mi; pr.xdi = x_di; pr.ofmi = hfb_mi; pr.ofdi = hfb_di;
    int prep_blocks = eb + 224 + MI_P / 64 + DI_P / 64;
    prep_kernel<<<prep_blocks, 256, 0, stream>>>(pr);

    // ---- scan (needs count) ----
    scan_part_kernel<<<dim3(NB_MI, 2), 256, 0, stream>>>(deg_di, deg_mi, row_di, row_mi, bsum);
    scan_sums_kernel<<<1, 128, 0, stream>>>(bsum, row_di, row_mi);
    scan_add_kernel<<<dim3(NB_MI, 2), 256, 0, stream>>>(bsum, row_di, row_mi);

    // ---- fused: fill || init GEMMs (h0 = x @ W^T + b + emb) ----
    FusedInit fi;
    fi.src = edge_src; fi.dst = edge_dst;
    fi.row_mi = row_mi; fi.row_di = row_di;
    fi.cur_mi = cur_mi; fi.cur_di = cur_di;
    fi.csr_mi = csr_mi; fi.csr_di = csr_di;
    fi.E = E; fi.nfill = eb;
    fi.Ami = hfb_mi; fi.Wmi = wWmi; fi.bmi = b_mi; fi.embmi = emb_mi;
    fi.Cmi = h_mi0; fi.Cfmi = hfa_mi;
    fi.Adi = hfb_di; fi.Wdi = wWdi; fi.bdi = b_di; fi.embdi = emb_di;
    fi.Cdi = h_di0; fi.Cfdi = hfa_di;
    int fused_blocks = eb + (MI_P / 128) * 2 + (DI_P / 64) * 2;
    fused_init_kernel<<<fused_blocks, 256, 0, stream>>>(fi);

    const int nmib_agg = (N_MI + 3) / 4, ndib_agg = (N_DI + 3) / 4;

    // ---- Layer 1: 128 -> 256, relu ----
    {
        FusedAgg fa{h_mi0, h_di0, row_di, csr_di, row_mi, csr_mi, aggdi, aggmi, nmib_agg};
        fused_agg_kernel<128><<<nmib_agg + ndib_agg, 256, 0, stream>>>(fa);
        FusedGemm fg;
        fg.Ami = aggmi; fg.Wlmi = wl1dm; fg.Rmi = hfa_mi; fg.Wrmi = wr1dm; fg.bmi = bl1_dm;
        fg.Cmi = h_mi1; fg.Cfmi = hfb_mi;
        fg.Adi = aggdi; fg.Wldi = wl1md; fg.Rdi = hfa_di; fg.Wrdi = wr1md; fg.bdi = bl1_md;
        fg.Cdi = h_di1; fg.Cfdi = hfb_di;
        fg.xmi = MI_P / 128; fg.xdi = DI_P / 64;
        fg.nmib = fg.xmi * 4; fg.Nmi = 256; fg.Ndi = 256; fg.relu = 1;
        fused_gemm_kernel<4, 2, 1><<<fg.nmib + fg.xdi * 4, 256, 0, stream>>>(fg);
    }

    // ---- Layer 2: 256 -> 128, relu ----
    {
        FusedAgg fa{h_mi1, h_di1, row_di, csr_di, row_mi, csr_mi, aggdi, aggmi, nmib_agg};
        fused_agg_kernel<256><<<nmib_agg + ndib_agg, 256, 0, stream>>>(fa);
        FusedGemm fg;
        fg.Ami = aggmi; fg.Wlmi = wl2dm; fg.Rmi = hfb_mi; fg.Wrmi = wr2dm; fg.bmi = bl2_dm;
        fg.Cmi = h_mi0; fg.Cfmi = hfa_mi;
        fg.Adi = aggdi; fg.Wldi = wl2md; fg.Rdi = hfb_di; fg.Wrdi = wr2md; fg.bdi = bl2_md;
        fg.Cdi = h_di0; fg.Cfdi = hfa_di;
        fg.xmi = MI_P / 128; fg.xdi = DI_P / 64;
        fg.nmib = fg.xmi * 2; fg.Nmi = 128; fg.Ndi = 128; fg.relu = 1;
        fused_gemm_kernel<8, 2, 1><<<fg.nmib + fg.xdi * 2, 256, 0, stream>>>(fg);
    }

    // ---- Layer 3: 128 -> 64, no relu ----
    {
        FusedAgg fa{h_mi0, h_di0, row_di, csr_di, row_mi, csr_mi, aggdi, aggmi, nmib_agg};
        fused_agg_kernel<128><<<nmib_agg + ndib_agg, 256, 0, stream>>>(fa);
        FusedGemm fg;
        fg.Ami = aggmi; fg.Wlmi = wl3dm; fg.Rmi = hfa_mi; fg.Wrmi = wr3dm; fg.bmi = bl3_dm;
        fg.Cmi = h_mi1; fg.Cfmi = nullptr;
        fg.Adi = aggdi; fg.Wldi = wl3md; fg.Rdi = hfa_di; fg.Wrdi = wr3md; fg.bdi = bl3_md;
        fg.Cdi = h_di1; fg.Cfdi = nullptr;
        fg.xmi = MI_P / 64; fg.xdi = DI_P / 64;
        fg.nmib = fg.xmi; fg.Nmi = 64; fg.Ndi = 64; fg.relu = 0;
        fused_gemm_kernel<4, 1, 1><<<fg.nmib + fg.xdi, 256, 0, stream>>>(fg);
    }

    // ---- classifier ----
    classify_kernel<<<((long)L * 16 + 255) / 256, 256, 0, stream>>>(
        h_mi1, h_di1, label_src, label_dst, out, L);
}